// Round 1
// baseline (786.422 us; speedup 1.0000x reference)
//
#include <hip/hip_runtime.h>
#include <cfloat>

// Problem constants
#define B_  16
#define N_  500   // INPUT_SIZE
#define S_  128   // SENTENCE_SIZE
#define D_  512
#define FO_ 128   // ori head dim
#define FI_ 64    // in/out head dim

// =====================================================================
// K1: projection GEMM. out[((b*4+h)*N + n)*F + f] =
//     relu( sum_d code[(b*N+n)*D + d] * W[(h*D+d)*F + f] + bias[h*F+f] )
// rows R = B*N = 8000 (125 tiles of 64), cols C = 4*F (C/64 tiles)
// =====================================================================
template<int F>
__global__ __launch_bounds__(256) void proj_kernel(const float* __restrict__ code,
                                                   const float* __restrict__ W,
                                                   const float* __restrict__ bias,
                                                   float* __restrict__ out)
{
    __shared__ float As[16][68];
    __shared__ float Bs[16][68];
    const int t  = threadIdx.x;
    const int tx = t & 15, ty = t >> 4;
    const int r0 = blockIdx.x * 64;
    const int c0 = blockIdx.y * 64;
    const int h  = c0 / F;
    const int fb = c0 % F;
    const float* Wh = W + (size_t)h * D_ * F + fb;

    float acc[4][4] = {};
    for (int k0 = 0; k0 < D_; k0 += 16) {
        { // stage A (k-major): 64 rows x 16 k
            const int kk = t & 15;
            const int rr = t >> 4;
            #pragma unroll
            for (int i = 0; i < 4; ++i)
                As[kk][rr + 16*i] = code[(size_t)(r0 + rr + 16*i) * D_ + k0 + kk];
        }
        { // stage B: 16 k x 64 cols (contiguous f in W)
            const int kk = t >> 4;
            const int c4 = (t & 15) * 4;
            *(float4*)&Bs[kk][c4] = *(const float4*)(Wh + (size_t)(k0 + kk) * F + c4);
        }
        __syncthreads();
        #pragma unroll
        for (int kk = 0; kk < 16; ++kk) {
            const float4 a  = *(const float4*)&As[kk][ty*4];
            const float4 bb = *(const float4*)&Bs[kk][tx*4];
            const float av[4] = {a.x, a.y, a.z, a.w};
            const float bv[4] = {bb.x, bb.y, bb.z, bb.w};
            #pragma unroll
            for (int i = 0; i < 4; ++i)
                #pragma unroll
                for (int j = 0; j < 4; ++j)
                    acc[i][j] = fmaf(av[i], bv[j], acc[i][j]);
        }
        __syncthreads();
    }
    #pragma unroll
    for (int i = 0; i < 4; ++i) {
        const int r = r0 + ty*4 + i;
        const int b = r / N_;
        const int n = r % N_;
        #pragma unroll
        for (int j = 0; j < 4; ++j) {
            const int c = c0 + tx*4 + j;
            float v = acc[i][j] + bias[c];
            v = v > 0.f ? v : 0.f;
            out[((size_t)(b*4 + h) * N_ + n) * F + (c % F)] = v;
        }
    }
}

// =====================================================================
// K2: maxsc[b,n,m] = max_h sum_f q[b,h,n,f]*k[b,h,m,f]   (q,k: B,4,N,128)
// =====================================================================
__global__ __launch_bounds__(256) void maxscore_kernel(const float* __restrict__ q,
                                                       const float* __restrict__ k,
                                                       float* __restrict__ maxsc)
{
    __shared__ float Qs[16][68];
    __shared__ float Ks[16][68];
    const int t  = threadIdx.x;
    const int tx = t & 15, ty = t >> 4;
    const int b  = blockIdx.x;
    const int n0 = blockIdx.y * 64;
    const int m0 = blockIdx.z * 64;

    float best[4][4];
    #pragma unroll
    for (int i = 0; i < 4; ++i)
        #pragma unroll
        for (int j = 0; j < 4; ++j) best[i][j] = -FLT_MAX;

    for (int h = 0; h < 4; ++h) {
        const float* qh = q + (size_t)(b*4 + h) * N_ * FO_;
        const float* kh = k + (size_t)(b*4 + h) * N_ * FO_;
        float acc[4][4] = {};
        for (int f0 = 0; f0 < FO_; f0 += 16) {
            const int ff = t & 15;
            const int rr = t >> 4;
            #pragma unroll
            for (int i = 0; i < 4; ++i) {
                const int n = n0 + rr + 16*i;
                const int m = m0 + rr + 16*i;
                Qs[ff][rr + 16*i] = (n < N_) ? qh[(size_t)n * FO_ + f0 + ff] : 0.f;
                Ks[ff][rr + 16*i] = (m < N_) ? kh[(size_t)m * FO_ + f0 + ff] : 0.f;
            }
            __syncthreads();
            #pragma unroll
            for (int kk = 0; kk < 16; ++kk) {
                const float4 a  = *(const float4*)&Qs[kk][ty*4];
                const float4 bb = *(const float4*)&Ks[kk][tx*4];
                const float av[4] = {a.x, a.y, a.z, a.w};
                const float bv[4] = {bb.x, bb.y, bb.z, bb.w};
                #pragma unroll
                for (int i = 0; i < 4; ++i)
                    #pragma unroll
                    for (int j = 0; j < 4; ++j)
                        acc[i][j] = fmaf(av[i], bv[j], acc[i][j]);
            }
            __syncthreads();
        }
        #pragma unroll
        for (int i = 0; i < 4; ++i)
            #pragma unroll
            for (int j = 0; j < 4; ++j)
                best[i][j] = fmaxf(best[i][j], acc[i][j]);
    }
    #pragma unroll
    for (int i = 0; i < 4; ++i) {
        const int n = n0 + ty*4 + i;
        if (n >= N_) continue;
        #pragma unroll
        for (int j = 0; j < 4; ++j) {
            const int m = m0 + tx*4 + j;
            if (m < N_) maxsc[((size_t)b * N_ + n) * N_ + m] = best[i][j];
        }
    }
}

// =====================================================================
// K3: sA[b,s,m] = sum_n sent[b,s,n] * maxsc[b,n,m]
// =====================================================================
__global__ __launch_bounds__(256) void sa_kernel(const float* __restrict__ sent,
                                                 const float* __restrict__ maxsc,
                                                 float* __restrict__ sA)
{
    __shared__ float As[16][68];
    __shared__ float Bs[16][68];
    const int t  = threadIdx.x;
    const int tx = t & 15, ty = t >> 4;
    const int b  = blockIdx.x;
    const int s0 = blockIdx.y * 64;
    const int m0 = blockIdx.z * 64;
    const float* A  = sent  + (size_t)b * S_ * N_;
    const float* Bm = maxsc + (size_t)b * N_ * N_;

    float acc[4][4] = {};
    for (int k0 = 0; k0 < N_; k0 += 16) {
        {
            const int kk = t & 15;
            const int rr = t >> 4;
            const int n  = k0 + kk;
            #pragma unroll
            for (int i = 0; i < 4; ++i)
                As[kk][rr + 16*i] = (n < N_) ? A[(size_t)(s0 + rr + 16*i) * N_ + n] : 0.f;
        }
        {
            const int kk = t >> 4;
            const int c4 = (t & 15) * 4;
            const int n  = k0 + kk;
            if (n < N_ && m0 + 63 < N_) {
                *(float4*)&Bs[kk][c4] = *(const float4*)&Bm[(size_t)n * N_ + m0 + c4];
            } else {
                #pragma unroll
                for (int j = 0; j < 4; ++j) {
                    const int m = m0 + c4 + j;
                    Bs[kk][c4 + j] = (n < N_ && m < N_) ? Bm[(size_t)n * N_ + m] : 0.f;
                }
            }
        }
        __syncthreads();
        #pragma unroll
        for (int kk = 0; kk < 16; ++kk) {
            const float4 a  = *(const float4*)&As[kk][ty*4];
            const float4 bb = *(const float4*)&Bs[kk][tx*4];
            const float av[4] = {a.x, a.y, a.z, a.w};
            const float bv[4] = {bb.x, bb.y, bb.z, bb.w};
            #pragma unroll
            for (int i = 0; i < 4; ++i)
                #pragma unroll
                for (int j = 0; j < 4; ++j)
                    acc[i][j] = fmaf(av[i], bv[j], acc[i][j]);
        }
        __syncthreads();
    }
    #pragma unroll
    for (int i = 0; i < 4; ++i) {
        const int s = s0 + ty*4 + i;   // s < 128 always
        #pragma unroll
        for (int j = 0; j < 4; ++j) {
            const int m = m0 + tx*4 + j;
            if (m < N_) sA[((size_t)b * S_ + s) * N_ + m] = acc[i][j];
        }
    }
}

// =====================================================================
// K4: out[b,s,d] = sum_m (sent[b,s,m]*sA[b,s,m]) * code[b,m,d]
//     written to d_out cols 0..511 with row stride 1024
// =====================================================================
__global__ __launch_bounds__(256) void outori_kernel(const float* __restrict__ sent,
                                                     const float* __restrict__ sA,
                                                     const float* __restrict__ code,
                                                     float* __restrict__ out)
{
    __shared__ float As[16][68];
    __shared__ float Bs[16][68];
    const int t  = threadIdx.x;
    const int tx = t & 15, ty = t >> 4;
    const int b  = blockIdx.x;
    const int s0 = blockIdx.y * 64;
    const int d0 = blockIdx.z * 64;

    float acc[4][4] = {};
    for (int k0 = 0; k0 < N_; k0 += 16) {
        {
            const int kk = t & 15;
            const int rr = t >> 4;
            const int m  = k0 + kk;
            #pragma unroll
            for (int i = 0; i < 4; ++i) {
                const size_t idx = ((size_t)b * S_ + s0 + rr + 16*i) * N_ + m;
                As[kk][rr + 16*i] = (m < N_) ? sent[idx] * sA[idx] : 0.f;
            }
        }
        {
            const int kk = t >> 4;
            const int c4 = (t & 15) * 4;
            const int m  = k0 + kk;
            float4 v = make_float4(0.f, 0.f, 0.f, 0.f);
            if (m < N_) v = *(const float4*)&code[((size_t)b * N_ + m) * D_ + d0 + c4];
            *(float4*)&Bs[kk][c4] = v;
        }
        __syncthreads();
        #pragma unroll
        for (int kk = 0; kk < 16; ++kk) {
            const float4 a  = *(const float4*)&As[kk][ty*4];
            const float4 bb = *(const float4*)&Bs[kk][tx*4];
            const float av[4] = {a.x, a.y, a.z, a.w};
            const float bv[4] = {bb.x, bb.y, bb.z, bb.w};
            #pragma unroll
            for (int i = 0; i < 4; ++i)
                #pragma unroll
                for (int j = 0; j < 4; ++j)
                    acc[i][j] = fmaf(av[i], bv[j], acc[i][j]);
        }
        __syncthreads();
    }
    #pragma unroll
    for (int i = 0; i < 4; ++i) {
        const int s = s0 + ty*4 + i;
        #pragma unroll
        for (int j = 0; j < 4; ++j) {
            const int d = d0 + tx*4 + j;
            out[((size_t)b * S_ + s) * 1024 + d] = acc[i][j];
        }
    }
}

// =====================================================================
// K5: qs[b,h,s,f] = sum_n sent[b,s,n] * proj[b,h,n,f]   (cols = 64)
// grid: (B*4, 2)
// =====================================================================
__global__ __launch_bounds__(256) void qs_kernel(const float* __restrict__ sent,
                                                 const float* __restrict__ proj,
                                                 float* __restrict__ qs)
{
    __shared__ float As[16][68];
    __shared__ float Bs[16][68];
    const int t  = threadIdx.x;
    const int tx = t & 15, ty = t >> 4;
    const int bh = blockIdx.x;
    const int b  = bh >> 2;
    const int s0 = blockIdx.y * 64;
    const float* A  = sent + (size_t)b * S_ * N_;
    const float* Bp = proj + (size_t)bh * N_ * FI_;

    float acc[4][4] = {};
    for (int k0 = 0; k0 < N_; k0 += 16) {
        {
            const int kk = t & 15;
            const int rr = t >> 4;
            const int n  = k0 + kk;
            #pragma unroll
            for (int i = 0; i < 4; ++i)
                As[kk][rr + 16*i] = (n < N_) ? A[(size_t)(s0 + rr + 16*i) * N_ + n] : 0.f;
        }
        {
            const int kk = t >> 4;
            const int c4 = (t & 15) * 4;
            const int n  = k0 + kk;
            float4 v = make_float4(0.f, 0.f, 0.f, 0.f);
            if (n < N_) v = *(const float4*)&Bp[(size_t)n * FI_ + c4];
            *(float4*)&Bs[kk][c4] = v;
        }
        __syncthreads();
        #pragma unroll
        for (int kk = 0; kk < 16; ++kk) {
            const float4 a  = *(const float4*)&As[kk][ty*4];
            const float4 bb = *(const float4*)&Bs[kk][tx*4];
            const float av[4] = {a.x, a.y, a.z, a.w};
            const float bv[4] = {bb.x, bb.y, bb.z, bb.w};
            #pragma unroll
            for (int i = 0; i < 4; ++i)
                #pragma unroll
                for (int j = 0; j < 4; ++j)
                    acc[i][j] = fmaf(av[i], bv[j], acc[i][j]);
        }
        __syncthreads();
    }
    #pragma unroll
    for (int i = 0; i < 4; ++i) {
        const int s = s0 + ty*4 + i;   // < 128
        #pragma unroll
        for (int j = 0; j < 4; ++j) {
            const int f = tx*4 + j;
            qs[((size_t)bh * S_ + s) * FI_ + f] = acc[i][j];
        }
    }
}

// =====================================================================
// K6/K7: fused small attention per (b,h,s-tile of 32):
//   IN : out[s,f] = sum_m sent[s,m]       * (qs[s]·k[m]) * v[m,f]
//   OUT: out[s,f] = fac[s] * sum_m (sent[s,m]-1) * (qs[s]·k[m]) * v[m,f]
//        fac[s] = inc[s] / (500 - inc[s]),  inc[s] = sum_n sent[b,s,n]
// =====================================================================
template<bool OUTMASK>
__global__ __launch_bounds__(256) void attn_kernel(const float* __restrict__ sent,
                                                   const float* __restrict__ qs,
                                                   const float* __restrict__ kp,
                                                   const float* __restrict__ vp,
                                                   float* __restrict__ out,
                                                   int col_base)
{
    const int b  = blockIdx.x;
    const int h  = blockIdx.y;
    const int s0 = blockIdx.z * 32;
    const int bh = b*4 + h;
    const int t  = threadIdx.x;

    __shared__ float qsS[32][68];
    __shared__ float Ks[16][68];
    __shared__ float Vs[16][68];
    __shared__ float Ps[32][17];
    __shared__ float sentS[32][16];
    __shared__ float incS[32];

    // load qs tile (32 x 64)
    #pragma unroll
    for (int i = 0; i < 2; ++i) {
        const int u  = t + i*256;
        const int s  = u >> 4;
        const int f4 = (u & 15) * 4;
        *(float4*)&qsS[s][f4] = *(const float4*)&qs[((size_t)bh * S_ + s0 + s) * FI_ + f4];
    }
    if (OUTMASK) {
        const int s  = t >> 3;
        const int p8 = t & 7;
        float part = 0.f;
        for (int n = p8; n < N_; n += 8)
            part += sent[((size_t)b * S_ + s0 + s) * N_ + n];
        part += __shfl_down(part, 4, 8);
        part += __shfl_down(part, 2, 8);
        part += __shfl_down(part, 1, 8);
        if (p8 == 0) incS[s] = part;
    }
    __syncthreads();

    float acc[8] = {};
    for (int m0 = 0; m0 < N_; m0 += 16) {
        { // stage K, V (16 x 64 each)
            const int row = t >> 4;
            const int c4  = (t & 15) * 4;
            const int m   = m0 + row;
            float4 kv = make_float4(0.f, 0.f, 0.f, 0.f), vv = kv;
            if (m < N_) {
                kv = *(const float4*)&kp[((size_t)bh * N_ + m) * FI_ + c4];
                vv = *(const float4*)&vp[((size_t)bh * N_ + m) * FI_ + c4];
            }
            *(float4*)&Ks[row][c4] = kv;
            *(float4*)&Vs[row][c4] = vv;
        }
        #pragma unroll
        for (int i = 0; i < 2; ++i) { // stage sent (32 x 16)
            const int u  = t + i*256;
            const int s  = u >> 4;
            const int mm = u & 15;
            const int m  = m0 + mm;
            sentS[s][mm] = (m < N_) ? sent[((size_t)b * S_ + s0 + s) * N_ + m] : 0.f;
        }
        __syncthreads();
        // phase 1: P[s][mm] = weight(sent) * (qs[s]·k[mm])
        #pragma unroll
        for (int i = 0; i < 2; ++i) {
            const int u  = t + i*256;
            const int s  = u >> 4;
            const int mm = u & 15;
            float p = 0.f;
            #pragma unroll
            for (int f = 0; f < FI_; f += 4) {
                const float4 a  = *(const float4*)&qsS[s][f];
                const float4 bb = *(const float4*)&Ks[mm][f];
                p = fmaf(a.x, bb.x, p); p = fmaf(a.y, bb.y, p);
                p = fmaf(a.z, bb.z, p); p = fmaf(a.w, bb.w, p);
            }
            const float sv = sentS[s][mm];
            Ps[s][mm] = OUTMASK ? (sv - 1.f) * p : sv * p;
        }
        __syncthreads();
        // phase 2: acc[f] += P[s][mm] * V[mm][f]
        {
            const int s  = t >> 3;
            const int f0 = (t & 7) * 8;
            #pragma unroll
            for (int mm = 0; mm < 16; ++mm) {
                const float w  = Ps[s][mm];
                const float4 v0 = *(const float4*)&Vs[mm][f0];
                const float4 v1 = *(const float4*)&Vs[mm][f0 + 4];
                acc[0] = fmaf(w, v0.x, acc[0]); acc[1] = fmaf(w, v0.y, acc[1]);
                acc[2] = fmaf(w, v0.z, acc[2]); acc[3] = fmaf(w, v0.w, acc[3]);
                acc[4] = fmaf(w, v1.x, acc[4]); acc[5] = fmaf(w, v1.y, acc[5]);
                acc[6] = fmaf(w, v1.z, acc[6]); acc[7] = fmaf(w, v1.w, acc[7]);
            }
        }
        __syncthreads();
    }
    {
        const int s  = t >> 3;
        const int f0 = (t & 7) * 8;
        float fac = 1.f;
        if (OUTMASK) {
            const float inc = incS[s];
            fac = inc / (500.f - inc);
        }
        const size_t o = ((size_t)b * S_ + s0 + s) * 1024 + col_base + h * FI_ + f0;
        #pragma unroll
        for (int j = 0; j < 8; ++j) out[o + j] = acc[j] * fac;
    }
}

// =====================================================================
extern "C" void kernel_launch(void* const* d_in, const int* in_sizes, int n_in,
                              void* d_out, int out_size, void* d_ws, size_t ws_size,
                              hipStream_t stream)
{
    const float* code   = (const float*)d_in[0];
    const float* sent   = (const float*)d_in[1];
    const float* Wq_ori = (const float*)d_in[2];
    const float* bq_ori = (const float*)d_in[3];
    const float* Wk_ori = (const float*)d_in[4];
    const float* bk_ori = (const float*)d_in[5];
    const float* Wq_in  = (const float*)d_in[6];
    const float* bq_in  = (const float*)d_in[7];
    const float* Wk_in  = (const float*)d_in[8];
    const float* bk_in  = (const float*)d_in[9];
    const float* Wv_in  = (const float*)d_in[10];
    const float* bv_in  = (const float*)d_in[11];
    const float* Wq_out = (const float*)d_in[12];
    const float* bq_out = (const float*)d_in[13];
    const float* Wk_out = (const float*)d_in[14];
    const float* bk_out = (const float*)d_in[15];
    const float* Wv_out = (const float*)d_in[16];
    const float* bv_out = (const float*)d_in[17];
    float* out = (float*)d_out;
    float* ws  = (float*)d_ws;

    // Phase 1 (ori) workspace
    float* q_ori = ws;                    // 16*4*500*128 = 4,096,000
    float* k_ori = ws + 4096000;          // 4,096,000
    float* maxsc = ws + 8192000;          // 16*500*500  = 4,000,000
    float* sA    = ws + 12192000;         // 16*128*500  = 1,024,000 (ends 13,216,000)
    // Phase 2 (in/out) workspace — reuses phase-1 regions that are dead by then
    float* qi     = ws;                   // each 16*4*500*64 = 2,048,000
    float* ki     = ws + 2048000;
    float* vi     = ws + 4096000;
    float* qo     = ws + 6144000;
    float* ko     = ws + 8192000;
    float* vo     = ws + 10240000;
    float* qs_in  = ws + 12288000;        // 16*4*128*64 = 524,288
    float* qs_out = ws + 12812288;        // ends 13,336,576 floats ≈ 53.3 MB

    const dim3 blk(256);

    // ---- ori branch ----
    proj_kernel<128><<<dim3(125, 8), blk, 0, stream>>>(code, Wq_ori, bq_ori, q_ori);
    proj_kernel<128><<<dim3(125, 8), blk, 0, stream>>>(code, Wk_ori, bk_ori, k_ori);
    maxscore_kernel<<<dim3(16, 8, 8), blk, 0, stream>>>(q_ori, k_ori, maxsc);
    sa_kernel<<<dim3(16, 2, 8), blk, 0, stream>>>(sent, maxsc, sA);
    outori_kernel<<<dim3(16, 2, 8), blk, 0, stream>>>(sent, sA, code, out);

    // ---- in/out projections (after out_ori: q_ori/k_ori/maxsc dead) ----
    proj_kernel<64><<<dim3(125, 4), blk, 0, stream>>>(code, Wq_in,  bq_in,  qi);
    proj_kernel<64><<<dim3(125, 4), blk, 0, stream>>>(code, Wk_in,  bk_in,  ki);
    proj_kernel<64><<<dim3(125, 4), blk, 0, stream>>>(code, Wv_in,  bv_in,  vi);
    proj_kernel<64><<<dim3(125, 4), blk, 0, stream>>>(code, Wq_out, bq_out, qo);
    proj_kernel<64><<<dim3(125, 4), blk, 0, stream>>>(code, Wk_out, bk_out, ko);
    proj_kernel<64><<<dim3(125, 4), blk, 0, stream>>>(code, Wv_out, bv_out, vo);

    // ---- qs = sent @ q-projection (factorized sAi/sAo) ----
    qs_kernel<<<dim3(64, 2), blk, 0, stream>>>(sent, qi, qs_in);
    qs_kernel<<<dim3(64, 2), blk, 0, stream>>>(sent, qo, qs_out);

    // ---- fused in/out attention ----
    attn_kernel<false><<<dim3(16, 4, 4), blk, 0, stream>>>(sent, qs_in,  ki, vi, out, 512);
    attn_kernel<true ><<<dim3(16, 4, 4), blk, 0, stream>>>(sent, qs_out, ko, vo, out, 768);
}

// Round 2
// 378.302 us; speedup vs baseline: 2.0788x; 2.0788x over previous
//
#include <hip/hip_runtime.h>
#include <cfloat>

#define B_  16
#define N_  500   // INPUT_SIZE
#define NP  512   // padded N
#define S_  128   // SENTENCE_SIZE
#define D_  512
#define FO  128   // ori head dim
#define FI  64    // in/out head dim

typedef unsigned short u16;
typedef __attribute__((ext_vector_type(8))) short bf8;
typedef __attribute__((ext_vector_type(4))) float f4;

#define MFMA(a,b,c) __builtin_amdgcn_mfma_f32_16x16x32_bf16((a),(b),(c),0,0,0)

__device__ __forceinline__ u16 f2b(float x){
    union{float f;unsigned u;} v; v.f=x;
    unsigned r = v.u + 0x7fffu + ((v.u>>16)&1u);
    return (u16)(r>>16);
}
__device__ __forceinline__ float b2f(u16 x){
    union{unsigned u;float f;} v; v.u=((unsigned)x)<<16; return v.f;
}
__device__ __forceinline__ bf8 ldb8(const u16* p){ return *(const bf8*)p; }

// =====================================================================
// prep_code: codeB[b][m][d] bf16 (m<500) and codeT[b][d][mP] bf16 (pad 0)
// grid (16, 8 mtile, 8 dtile), block 256
// =====================================================================
__global__ __launch_bounds__(256) void prep_code(const float* __restrict__ code,
                                                 u16* __restrict__ codeB,
                                                 u16* __restrict__ codeT)
{
    __shared__ float T[64][65];
    const int b = blockIdx.x, m0 = blockIdx.y*64, d0 = blockIdx.z*64;
    const int t = threadIdx.x;
    #pragma unroll
    for (int i=0;i<16;++i){
        int idx = t + i*256; int rr = idx>>6, cc = idx&63;
        int m = m0+rr;
        T[rr][cc] = (m < N_) ? code[((size_t)b*N_+m)*D_ + d0+cc] : 0.f;
    }
    __syncthreads();
    #pragma unroll
    for (int i=0;i<16;++i){
        int idx=t+i*256; int rr=idx>>6, cc=idx&63; int m=m0+rr;
        if (m<N_) codeB[((size_t)b*N_+m)*D_ + d0+cc] = f2b(T[rr][cc]);
    }
    #pragma unroll
    for (int i=0;i<16;++i){
        int idx=t+i*256; int dd=idx>>6, mm=idx&63;
        codeT[((size_t)b*D_ + d0+dd)*NP + m0+mm] = f2b(T[mm][dd]);
    }
}

// =====================================================================
// prep_sent: sentB[b][s][nP] bf16 (pad 0) + inc[b][s] = sum_n sent
// grid (16,128), block 128
// =====================================================================
__global__ __launch_bounds__(128) void prep_sent(const float* __restrict__ sent,
                                                 u16* __restrict__ sentB,
                                                 float* __restrict__ inc)
{
    const int b=blockIdx.x, s=blockIdx.y, t=threadIdx.x;
    const float* row = sent + ((size_t)b*S_+s)*N_;
    float4 v = make_float4(0.f,0.f,0.f,0.f);
    const int n = t*4;
    if (n < N_) v = *(const float4*)(row+n);     // 500 % 4 == 0
    float sum = v.x+v.y+v.z+v.w;
    ushort4 o; o.x=f2b(v.x); o.y=f2b(v.y); o.z=f2b(v.z); o.w=f2b(v.w);
    *(ushort4*)&sentB[((size_t)b*S_+s)*NP + n] = o;
    #pragma unroll
    for (int off=32; off; off>>=1) sum += __shfl_down(sum, off);
    __shared__ float ls[2];
    if ((t&63)==0) ls[t>>6]=sum;
    __syncthreads();
    if (t==0) inc[b*S_+s] = ls[0]+ls[1];
}

// =====================================================================
// prep_w: WT[h][f][d] bf16 = W[h][d][f].  grid (4, F/64, 8), block 256
// =====================================================================
__global__ __launch_bounds__(256) void prep_w(const float* __restrict__ W,
                                              u16* __restrict__ WT, int F)
{
    __shared__ float T[64][65];
    const int h=blockIdx.x, f0=blockIdx.y*64, d0=blockIdx.z*64, t=threadIdx.x;
    #pragma unroll
    for (int i=0;i<16;++i){
        int idx=t+i*256; int rr=idx>>6, cc=idx&63;
        T[rr][cc] = W[((size_t)h*D_ + d0+rr)*F + f0+cc];
    }
    __syncthreads();
    #pragma unroll
    for (int i=0;i<16;++i){
        int idx=t+i*256; int ff=idx>>6, dd=idx&63;
        WT[((size_t)h*F + f0+ff)*D_ + d0+dd] = f2b(T[dd][ff]);
    }
}

// zero pad cols n in [500,512) of 4 arrays laid out [64bh][64f][512]
__global__ __launch_bounds__(256) void zero_pad4(u16* a0, u16* a1, u16* a2, u16* a3)
{
    u16* arr4[4] = {a0,a1,a2,a3};
    u16* base = arr4[blockIdx.y] + (size_t)blockIdx.x*FI*NP;
    for (int idx=threadIdx.x; idx<FI*12; idx+=256){
        int f = idx/12, n = N_ + idx%12;
        base[(size_t)f*NP + n] = 0;
    }
}

// =====================================================================
// proj_mfma: P = relu(codeB @ W + b).  1 wave = 16 rows x 64 cols.
// A: codeB [8000][512]; B: WT[h][f][512].
// WN: outN[bh][n][F] row-major; WTR: outT[bh][f][512] transposed.
// grid (500, 4F/64), block 64
// =====================================================================
template<int F, int WN, int WTR>
__global__ __launch_bounds__(64) void proj_mfma(const u16* __restrict__ codeB,
                                                const u16* __restrict__ WT,
                                                const float* __restrict__ bias,
                                                u16* __restrict__ outN,
                                                u16* __restrict__ outT)
{
    const int l = threadIdx.x, lane16 = l&15, lq = l>>4;
    const int r0 = blockIdx.x*16;
    const int c0 = blockIdx.y*64;
    const int h = c0 / F, fb = c0 % F;
    const u16* aptr = codeB + (size_t)(r0+lane16)*D_ + lq*8;
    const u16* bp[4];
    #pragma unroll
    for (int ct=0; ct<4; ++ct)
        bp[ct] = WT + ((size_t)h*F + fb + ct*16 + lane16)*D_ + lq*8;

    f4 acc[4] = {};
    for (int k0=0;k0<D_;k0+=32){
        bf8 a = ldb8(aptr+k0);
        #pragma unroll
        for (int ct=0;ct<4;++ct)
            acc[ct] = MFMA(a, ldb8(bp[ct]+k0), acc[ct]);
    }
    const int rbase = r0 + lq*4;
    const int b  = rbase / N_;      // 500%4==0 -> 4 rows never cross b
    const int nb = rbase % N_;
    #pragma unroll
    for (int ct=0;ct<4;++ct){
        const int f = fb + ct*16 + lane16;
        const float bv = bias[h*F + f];
        float v[4];
        #pragma unroll
        for (int reg=0;reg<4;++reg){
            float x = acc[ct][reg] + bv;
            v[reg] = x>0.f ? x : 0.f;
        }
        if (WN){
            u16* o = outN + (((size_t)(b*4+h))*N_ + nb)*F + f;
            #pragma unroll
            for (int reg=0;reg<4;++reg) o[(size_t)reg*F] = f2b(v[reg]);
        }
        if (WTR){
            ushort4 o; o.x=f2b(v[0]); o.y=f2b(v[1]); o.z=f2b(v[2]); o.w=f2b(v[3]);
            *(ushort4*)&outT[(((size_t)(b*4+h))*F + f)*NP + nb] = o;
        }
    }
}

// =====================================================================
// ms_mfma: maxscT[b][m][n] = max_h q[bh][n][:]·k[bh][m][:]  (bf16 out)
// 1 wave = 32 n-rows x 64 m-cols. grid (16, 16, 8), block 64
// =====================================================================
__global__ __launch_bounds__(64) void ms_mfma(const u16* __restrict__ q,
                                              const u16* __restrict__ k,
                                              u16* __restrict__ maxscT)
{
    const int l=threadIdx.x, lane16=l&15, lq=l>>4;
    const int b=blockIdx.x, n0=blockIdx.y*32, m0=blockIdx.z*64;
    f4 best[2][4];
    #pragma unroll
    for(int rt=0;rt<2;++rt)
        #pragma unroll
        for(int ct=0;ct<4;++ct)
            #pragma unroll
            for(int i=0;i<4;++i) best[rt][ct][i] = -FLT_MAX;

    for (int h=0;h<4;++h){
        const size_t base = ((size_t)(b*4+h))*N_*FO;
        const u16 *ap[2], *bpp[4];
        #pragma unroll
        for(int rt=0;rt<2;++rt){ int n=n0+rt*16+lane16; if(n>N_-1)n=N_-1; ap[rt]=q+base+(size_t)n*FO+lq*8; }
        #pragma unroll
        for(int ct=0;ct<4;++ct){ int m=m0+ct*16+lane16; if(m>N_-1)m=N_-1; bpp[ct]=k+base+(size_t)m*FO+lq*8; }
        f4 acc[2][4] = {};
        #pragma unroll
        for (int k0=0;k0<FO;k0+=32){
            bf8 a0=ldb8(ap[0]+k0), a1=ldb8(ap[1]+k0);
            #pragma unroll
            for(int ct=0;ct<4;++ct){
                bf8 bb=ldb8(bpp[ct]+k0);
                acc[0][ct]=MFMA(a0,bb,acc[0][ct]);
                acc[1][ct]=MFMA(a1,bb,acc[1][ct]);
            }
        }
        #pragma unroll
        for(int rt=0;rt<2;++rt)
            #pragma unroll
            for(int ct=0;ct<4;++ct)
                #pragma unroll
                for(int i=0;i<4;++i) best[rt][ct][i] = fmaxf(best[rt][ct][i], acc[rt][ct][i]);
    }
    #pragma unroll
    for(int rt=0;rt<2;++rt)
        #pragma unroll
        for(int ct=0;ct<4;++ct){
            const int m = m0+ct*16+lane16;
            const int nb = n0+rt*16+lq*4;
            ushort4 o; o.x=f2b(best[rt][ct][0]); o.y=f2b(best[rt][ct][1]);
            o.z=f2b(best[rt][ct][2]); o.w=f2b(best[rt][ct][3]);
            *(ushort4*)&maxscT[((size_t)b*NP+m)*NP + nb] = o;
        }
}

// =====================================================================
// sa_mfma: sAm[b][s][m] = sent[s][m] * sum_n sentB[s][n]*maxscT[m][n]
// 1 wave = 32 s x 64 m. grid (16,4,8), block 64
// =====================================================================
__global__ __launch_bounds__(64) void sa_mfma(const u16* __restrict__ sentB,
                                              const u16* __restrict__ maxscT,
                                              u16* __restrict__ sAm)
{
    const int l=threadIdx.x, lane16=l&15, lq=l>>4;
    const int b=blockIdx.x, s0=blockIdx.y*32, m0=blockIdx.z*64;
    const u16 *ap[2], *bpp[4];
    #pragma unroll
    for(int rt=0;rt<2;++rt) ap[rt]  = sentB  + ((size_t)b*S_ + s0+rt*16+lane16)*NP + lq*8;
    #pragma unroll
    for(int ct=0;ct<4;++ct) bpp[ct] = maxscT + ((size_t)b*NP + m0+ct*16+lane16)*NP + lq*8;
    f4 acc[2][4] = {};
    for (int k0=0;k0<NP;k0+=32){
        bf8 a0=ldb8(ap[0]+k0), a1=ldb8(ap[1]+k0);
        #pragma unroll
        for(int ct=0;ct<4;++ct){
            bf8 bb=ldb8(bpp[ct]+k0);
            acc[0][ct]=MFMA(a0,bb,acc[0][ct]);
            acc[1][ct]=MFMA(a1,bb,acc[1][ct]);
        }
    }
    #pragma unroll
    for(int rt=0;rt<2;++rt)
        #pragma unroll
        for(int ct=0;ct<4;++ct){
            const int m = m0+ct*16+lane16;
            #pragma unroll
            for(int reg=0;reg<4;++reg){
                const int s = s0+rt*16+lq*4+reg;
                const float sv = b2f(sentB[((size_t)b*S_+s)*NP+m]);
                sAm[((size_t)b*S_+s)*NP+m] = f2b(acc[rt][ct][reg]*sv);
            }
        }
}

// =====================================================================
// oo_mfma: out[b][s][d] = sum_m sAm[s][m]*codeT[d][m]  -> d_out cols 0..511
// grid (16,4,8), block 64
// =====================================================================
__global__ __launch_bounds__(64) void oo_mfma(const u16* __restrict__ sAm,
                                              const u16* __restrict__ codeT,
                                              float* __restrict__ out)
{
    const int l=threadIdx.x, lane16=l&15, lq=l>>4;
    const int b=blockIdx.x, s0=blockIdx.y*32, d0=blockIdx.z*64;
    const u16 *ap[2], *bpp[4];
    #pragma unroll
    for(int rt=0;rt<2;++rt) ap[rt]  = sAm   + ((size_t)b*S_ + s0+rt*16+lane16)*NP + lq*8;
    #pragma unroll
    for(int ct=0;ct<4;++ct) bpp[ct] = codeT + ((size_t)b*D_ + d0+ct*16+lane16)*NP + lq*8;
    f4 acc[2][4] = {};
    for (int k0=0;k0<NP;k0+=32){
        bf8 a0=ldb8(ap[0]+k0), a1=ldb8(ap[1]+k0);
        #pragma unroll
        for(int ct=0;ct<4;++ct){
            bf8 bb=ldb8(bpp[ct]+k0);
            acc[0][ct]=MFMA(a0,bb,acc[0][ct]);
            acc[1][ct]=MFMA(a1,bb,acc[1][ct]);
        }
    }
    #pragma unroll
    for(int rt=0;rt<2;++rt)
        #pragma unroll
        for(int ct=0;ct<4;++ct){
            const int d = d0+ct*16+lane16;
            #pragma unroll
            for(int reg=0;reg<4;++reg){
                const int s = s0+rt*16+lq*4+reg;
                out[((size_t)b*S_+s)*1024 + d] = acc[rt][ct][reg];
            }
        }
}

// =====================================================================
// qs_mfma: qs[bh][s][f] = sum_n sentB[b][s][n]*qT[bh][f][n]   (bf16 out)
// grid (64,4), block 64
// =====================================================================
__global__ __launch_bounds__(64) void qs_mfma(const u16* __restrict__ sentB,
                                              const u16* __restrict__ qT,
                                              u16* __restrict__ qsO)
{
    const int l=threadIdx.x, lane16=l&15, lq=l>>4;
    const int bh=blockIdx.x, b=bh>>2, s0=blockIdx.y*32;
    const u16 *ap[2], *bpp[4];
    #pragma unroll
    for(int rt=0;rt<2;++rt) ap[rt]  = sentB + ((size_t)b*S_ + s0+rt*16+lane16)*NP + lq*8;
    #pragma unroll
    for(int ct=0;ct<4;++ct) bpp[ct] = qT + ((size_t)bh*FI + ct*16+lane16)*NP + lq*8;
    f4 acc[2][4] = {};
    for (int k0=0;k0<NP;k0+=32){
        bf8 a0=ldb8(ap[0]+k0), a1=ldb8(ap[1]+k0);
        #pragma unroll
        for(int ct=0;ct<4;++ct){
            bf8 bb=ldb8(bpp[ct]+k0);
            acc[0][ct]=MFMA(a0,bb,acc[0][ct]);
            acc[1][ct]=MFMA(a1,bb,acc[1][ct]);
        }
    }
    #pragma unroll
    for(int rt=0;rt<2;++rt)
        #pragma unroll
        for(int ct=0;ct<4;++ct){
            const int f = ct*16+lane16;
            #pragma unroll
            for(int reg=0;reg<4;++reg){
                const int s = s0+rt*16+lq*4+reg;
                qsO[((size_t)bh*S_+s)*FI + f] = f2b(acc[rt][ct][reg]);
            }
        }
}

// =====================================================================
// attn_mfma<OUTB>: per (bh, 32 s-rows):
//   P[s][m] = w(s,m) * qs[s]·k[m];  O[s][f] += P[s][m]*v[m][f]
//   w = sent (in) or sent-1 for m<500 else 0 (out); out *= fac (out branch)
// grid (64,4), block 64.  LDS: P [32][72] bf16
// =====================================================================
template<int OUTB>
__global__ __launch_bounds__(64) void attn_mfma(const u16* __restrict__ qsO,
                                                const u16* __restrict__ kproj,
                                                const u16* __restrict__ vT,
                                                const u16* __restrict__ sentB,
                                                const float* __restrict__ inc,
                                                float* __restrict__ out,
                                                int colbase)
{
    __shared__ u16 P[32][72];
    const int l=threadIdx.x, lane16=l&15, lq=l>>4;
    const int bh=blockIdx.x, b=bh>>2, h=bh&3, s0=blockIdx.y*32;
    const u16* aq[2];
    #pragma unroll
    for(int rt=0;rt<2;++rt) aq[rt] = qsO + ((size_t)bh*S_ + s0+rt*16+lane16)*FI + lq*8;

    f4 accO[2][4] = {};
    for (int m0=0; m0<NP; m0+=64){
        // ---- QK ----
        f4 p[2][4] = {};
        const u16* bpp[4];
        #pragma unroll
        for(int ct=0;ct<4;++ct){
            int m=m0+ct*16+lane16; if(m>N_-1)m=N_-1;
            bpp[ct] = kproj + ((size_t)bh*N_+m)*FI + lq*8;
        }
        #pragma unroll
        for (int kk=0; kk<FI; kk+=32){
            bf8 a0=ldb8(aq[0]+kk), a1=ldb8(aq[1]+kk);
            #pragma unroll
            for(int ct=0;ct<4;++ct){
                bf8 bb=ldb8(bpp[ct]+kk);
                p[0][ct]=MFMA(a0,bb,p[0][ct]);
                p[1][ct]=MFMA(a1,bb,p[1][ct]);
            }
        }
        // ---- weight + store to LDS ----
        #pragma unroll
        for(int rt=0;rt<2;++rt)
            #pragma unroll
            for(int ct=0;ct<4;++ct){
                const int m = m0+ct*16+lane16;
                #pragma unroll
                for(int reg=0;reg<4;++reg){
                    const int s = s0+rt*16+lq*4+reg;
                    const float sv = b2f(sentB[((size_t)b*S_+s)*NP+m]);
                    float w;
                    if (OUTB) w = (m<N_) ? (sv-1.f) : 0.f;
                    else      w = sv;                      // pad sv==0
                    P[rt*16+lq*4+reg][ct*16+lane16] = f2b(p[rt][ct][reg]*w);
                }
            }
        __syncthreads();
        // ---- PV ----
        #pragma unroll
        for (int kk2=0; kk2<64; kk2+=32){
            bf8 a2[2];
            #pragma unroll
            for(int rt=0;rt<2;++rt) a2[rt] = *(const bf8*)&P[rt*16+lane16][kk2+lq*8];
            #pragma unroll
            for(int ct=0;ct<4;++ct){
                const int f = ct*16+lane16;
                bf8 vv = ldb8(vT + ((size_t)bh*FI+f)*NP + m0+kk2+lq*8);
                accO[0][ct]=MFMA(a2[0],vv,accO[0][ct]);
                accO[1][ct]=MFMA(a2[1],vv,accO[1][ct]);
            }
        }
        __syncthreads();
    }
    #pragma unroll
    for(int rt=0;rt<2;++rt)
        #pragma unroll
        for(int ct=0;ct<4;++ct){
            const int f = ct*16+lane16;
            #pragma unroll
            for(int reg=0;reg<4;++reg){
                const int s = s0+rt*16+lq*4+reg;
                float fac = 1.f;
                if (OUTB){ const float ic = inc[b*S_+s]; fac = ic/(500.f-ic); }
                out[((size_t)b*S_+s)*1024 + colbase + h*FI + f] = accO[rt][ct][reg]*fac;
            }
        }
}

// =====================================================================
extern "C" void kernel_launch(void* const* d_in, const int* in_sizes, int n_in,
                              void* d_out, int out_size, void* d_ws, size_t ws_size,
                              hipStream_t stream)
{
    const float* code   = (const float*)d_in[0];
    const float* sent   = (const float*)d_in[1];
    const float* Wq_ori = (const float*)d_in[2];
    const float* bq_ori = (const float*)d_in[3];
    const float* Wk_ori = (const float*)d_in[4];
    const float* bk_ori = (const float*)d_in[5];
    const float* Wq_in  = (const float*)d_in[6];
    const float* bq_in  = (const float*)d_in[7];
    const float* Wk_in  = (const float*)d_in[8];
    const float* bk_in  = (const float*)d_in[9];
    const float* Wv_in  = (const float*)d_in[10];
    const float* bv_in  = (const float*)d_in[11];
    const float* Wq_out = (const float*)d_in[12];
    const float* bq_out = (const float*)d_in[13];
    const float* Wk_out = (const float*)d_in[14];
    const float* bk_out = (const float*)d_in[15];
    const float* Wv_out = (const float*)d_in[16];
    const float* bv_out = (const float*)d_in[17];
    float* out = (float*)d_out;

    char* w = (char*)d_ws;
    u16*   codeB  = (u16*)(w);                  // 8,192,000 B
    u16*   WTqo   = (u16*)(w + 8192000);        // 524,288
    u16*   WTko   = (u16*)(w + 8716288);        // 524,288
    u16*   WTqi   = (u16*)(w + 9240576);        // 262,144 each
    u16*   WTki   = (u16*)(w + 9502720);
    u16*   WTvi   = (u16*)(w + 9764864);
    u16*   WTqu   = (u16*)(w + 10027008);
    u16*   WTku   = (u16*)(w + 10289152);
    u16*   WTvu   = (u16*)(w + 10551296);
    u16*   sentB  = (u16*)(w + 10813440);       // 2,097,152
    float* incp   = (float*)(w + 12910592);     // 8,192
    char*  S      = w + 12918784;
    // phase B
    u16* q_ori  = (u16*)(S);                    // 8,192,000
    u16* k_ori  = (u16*)(S + 8192000);          // 8,192,000
    u16* maxscT = (u16*)(S + 16384000);         // 8,388,608
    u16* sAm    = (u16*)(S + 24772608);         // 2,097,152
    u16* codeT  = (u16*)(S + 26869760);         // 8,388,608  (peak ~48.2 MB)
    // phase C overlay (after oo_mfma)
    u16* k_in   = (u16*)(S);                    // 4,096,000
    u16* k_out  = (u16*)(S + 4096000);
    u16* qT_in  = (u16*)(S + 8192000);          // 4,194,304 each
    u16* qT_out = (u16*)(S + 12386304);
    u16* vT_in  = (u16*)(S + 16580608);
    u16* vT_out = (u16*)(S + 20774912);
    u16* qs_in  = (u16*)(S + 24969216);         // 1,048,576 each
    u16* qs_out = (u16*)(S + 26017792);

    // ---- prep ----
    prep_code<<<dim3(16,8,8), 256, 0, stream>>>(code, codeB, codeT);
    prep_sent<<<dim3(16,128), 128, 0, stream>>>(sent, sentB, incp);
    prep_w<<<dim3(4,2,8), 256, 0, stream>>>(Wq_ori, WTqo, FO);
    prep_w<<<dim3(4,2,8), 256, 0, stream>>>(Wk_ori, WTko, FO);
    prep_w<<<dim3(4,1,8), 256, 0, stream>>>(Wq_in,  WTqi, FI);
    prep_w<<<dim3(4,1,8), 256, 0, stream>>>(Wk_in,  WTki, FI);
    prep_w<<<dim3(4,1,8), 256, 0, stream>>>(Wv_in,  WTvi, FI);
    prep_w<<<dim3(4,1,8), 256, 0, stream>>>(Wq_out, WTqu, FI);
    prep_w<<<dim3(4,1,8), 256, 0, stream>>>(Wk_out, WTku, FI);
    prep_w<<<dim3(4,1,8), 256, 0, stream>>>(Wv_out, WTvu, FI);

    // ---- ori branch ----
    proj_mfma<FO,1,0><<<dim3(500,8), 64, 0, stream>>>(codeB, WTqo, bq_ori, q_ori, nullptr);
    proj_mfma<FO,1,0><<<dim3(500,8), 64, 0, stream>>>(codeB, WTko, bk_ori, k_ori, nullptr);
    ms_mfma<<<dim3(16,16,8), 64, 0, stream>>>(q_ori, k_ori, maxscT);
    sa_mfma<<<dim3(16,4,8), 64, 0, stream>>>(sentB, maxscT, sAm);
    oo_mfma<<<dim3(16,4,8), 64, 0, stream>>>(sAm, codeT, out);

    // ---- in/out branch (phase B scratch now dead) ----
    zero_pad4<<<dim3(64,4), 256, 0, stream>>>(qT_in, qT_out, vT_in, vT_out);
    proj_mfma<FI,0,1><<<dim3(500,4), 64, 0, stream>>>(codeB, WTqi, bq_in,  nullptr, qT_in);
    proj_mfma<FI,1,0><<<dim3(500,4), 64, 0, stream>>>(codeB, WTki, bk_in,  k_in,  nullptr);
    proj_mfma<FI,0,1><<<dim3(500,4), 64, 0, stream>>>(codeB, WTvi, bv_in,  nullptr, vT_in);
    proj_mfma<FI,0,1><<<dim3(500,4), 64, 0, stream>>>(codeB, WTqu, bq_out, nullptr, qT_out);
    proj_mfma<FI,1,0><<<dim3(500,4), 64, 0, stream>>>(codeB, WTku, bk_out, k_out, nullptr);
    proj_mfma<FI,0,1><<<dim3(500,4), 64, 0, stream>>>(codeB, WTvu, bv_out, nullptr, vT_out);

    qs_mfma<<<dim3(64,4), 64, 0, stream>>>(sentB, qT_in,  qs_in);
    qs_mfma<<<dim3(64,4), 64, 0, stream>>>(sentB, qT_out, qs_out);

    attn_mfma<0><<<dim3(64,4), 64, 0, stream>>>(qs_in,  k_in,  vT_in,  sentB, incp, out, 512);
    attn_mfma<1><<<dim3(64,4), 64, 0, stream>>>(qs_out, k_out, vT_out, sentB, incp, out, 768);
}

// Round 3
// 284.389 us; speedup vs baseline: 2.7653x; 1.3302x over previous
//
#include <hip/hip_runtime.h>
#include <cfloat>

#define B_  16
#define N_  500   // INPUT_SIZE
#define NP  512   // padded N
#define S_  128   // SENTENCE_SIZE
#define D_  512
#define FO  128   // ori head dim
#define FI  64    // in/out head dim

typedef unsigned short u16;
typedef __attribute__((ext_vector_type(8))) short bf8;
typedef __attribute__((ext_vector_type(4))) float f4;

#define MFMA(a,b,c) __builtin_amdgcn_mfma_f32_16x16x32_bf16((a),(b),(c),0,0,0)

__device__ __forceinline__ u16 f2b(float x){
    union{float f;unsigned u;} v; v.f=x;
    unsigned r = v.u + 0x7fffu + ((v.u>>16)&1u);
    return (u16)(r>>16);
}
__device__ __forceinline__ float b2f(u16 x){
    union{unsigned u;float f;} v; v.u=((unsigned)x)<<16; return v.f;
}
__device__ __forceinline__ bf8 ldb8(const u16* p){ return *(const bf8*)p; }

// =====================================================================
// prep_code: codeB[b][m][d] bf16 (m<500) and codeT[b][d][mP] bf16 (pad 0)
// grid (16, 8 mtile, 8 dtile), block 256
// =====================================================================
__global__ __launch_bounds__(256) void prep_code(const float* __restrict__ code,
                                                 u16* __restrict__ codeB,
                                                 u16* __restrict__ codeT)
{
    __shared__ float T[64][65];
    const int b = blockIdx.x, m0 = blockIdx.y*64, d0 = blockIdx.z*64;
    const int t = threadIdx.x;
    #pragma unroll
    for (int i=0;i<16;++i){
        int idx = t + i*256; int rr = idx>>6, cc = idx&63;
        int m = m0+rr;
        T[rr][cc] = (m < N_) ? code[((size_t)b*N_+m)*D_ + d0+cc] : 0.f;
    }
    __syncthreads();
    #pragma unroll
    for (int i=0;i<16;++i){
        int idx=t+i*256; int rr=idx>>6, cc=idx&63; int m=m0+rr;
        if (m<N_) codeB[((size_t)b*N_+m)*D_ + d0+cc] = f2b(T[rr][cc]);
    }
    #pragma unroll
    for (int i=0;i<16;++i){
        int idx=t+i*256; int dd=idx>>6, mm=idx&63;
        codeT[((size_t)b*D_ + d0+dd)*NP + m0+mm] = f2b(T[mm][dd]);
    }
}

// =====================================================================
// prep_sent: sentB[b][s][nP] bf16 (pad 0) + inc[b][s] = sum_n sent
// grid (16,128), block 128
// =====================================================================
__global__ __launch_bounds__(128) void prep_sent(const float* __restrict__ sent,
                                                 u16* __restrict__ sentB,
                                                 float* __restrict__ inc)
{
    const int b=blockIdx.x, s=blockIdx.y, t=threadIdx.x;
    const float* row = sent + ((size_t)b*S_+s)*N_;
    float4 v = make_float4(0.f,0.f,0.f,0.f);
    const int n = t*4;
    if (n < N_) v = *(const float4*)(row+n);     // 500 % 4 == 0
    float sum = v.x+v.y+v.z+v.w;
    ushort4 o; o.x=f2b(v.x); o.y=f2b(v.y); o.z=f2b(v.z); o.w=f2b(v.w);
    *(ushort4*)&sentB[((size_t)b*S_+s)*NP + n] = o;
    #pragma unroll
    for (int off=32; off; off>>=1) sum += __shfl_down(sum, off);
    __shared__ float ls[2];
    if ((t&63)==0) ls[t>>6]=sum;
    __syncthreads();
    if (t==0) inc[b*S_+s] = ls[0]+ls[1];
}

// =====================================================================
// prep_w_all: one launch for all 8 weight transposes.
// slots: 0/1 Wq_ori(f-tile0/1), 2/3 Wk_ori(f0/1), 4..9 FI weights
// grid (4 h, 10 slots, 8 dtile), block 256
// =====================================================================
struct PWAll { const float* W[8]; u16* WT[8]; };
__global__ __launch_bounds__(256) void prep_w_all(PWAll a)
{
    const int slot = blockIdx.y;
    const int widx = slot<4 ? (slot>>1) : slot-2;
    const int ftile= slot<4 ? (slot&1)  : 0;
    const int F    = slot<4 ? 128 : 64;
    const float* W = a.W[widx];
    u16* WT        = a.WT[widx];
    __shared__ float T[64][65];
    const int h=blockIdx.x, f0=ftile*64, d0=blockIdx.z*64, t=threadIdx.x;
    #pragma unroll
    for (int i=0;i<16;++i){
        int idx=t+i*256; int rr=idx>>6, cc=idx&63;
        T[rr][cc] = W[((size_t)h*D_ + d0+rr)*F + f0+cc];
    }
    __syncthreads();
    #pragma unroll
    for (int i=0;i<16;++i){
        int idx=t+i*256; int ff=idx>>6, dd=idx&63;
        WT[((size_t)h*F + f0+ff)*D_ + d0+dd] = f2b(T[dd][ff]);
    }
}

// zero pad cols n in [500,512) of 4 arrays laid out [64bh][64f][512]
__global__ __launch_bounds__(256) void zero_pad4(u16* a0, u16* a1, u16* a2, u16* a3)
{
    u16* arr4[4] = {a0,a1,a2,a3};
    u16* base = arr4[blockIdx.y] + (size_t)blockIdx.x*FI*NP;
    for (int idx=threadIdx.x; idx<FI*12; idx+=256){
        int f = idx/12, n = N_ + idx%12;
        base[(size_t)f*NP + n] = 0;
    }
}

// =====================================================================
// proj_fo: ori projections (q,k) batched. F=128, row-major out.
// grid (500, 8 ctile, 2 slot), block 64
// =====================================================================
struct ProjFO { const u16* WT[2]; const float* bias[2]; u16* outN[2]; };
__global__ __launch_bounds__(64) void proj_fo(const u16* __restrict__ codeB, ProjFO a)
{
    const int slot = blockIdx.z;
    const u16* WT = a.WT[slot];
    const float* bias = a.bias[slot];
    u16* outN = a.outN[slot];

    const int l = threadIdx.x, lane16 = l&15, lq = l>>4;
    const int r0 = blockIdx.x*16;
    const int c0 = blockIdx.y*64;
    const int h = c0 / FO, fb = c0 % FO;
    const u16* aptr = codeB + (size_t)(r0+lane16)*D_ + lq*8;
    const u16* bp[4];
    #pragma unroll
    for (int ct=0; ct<4; ++ct)
        bp[ct] = WT + ((size_t)h*FO + fb + ct*16 + lane16)*D_ + lq*8;

    f4 acc[4] = {};
    for (int k0=0;k0<D_;k0+=32){
        bf8 av = ldb8(aptr+k0);
        #pragma unroll
        for (int ct=0;ct<4;++ct)
            acc[ct] = MFMA(av, ldb8(bp[ct]+k0), acc[ct]);
    }
    const int rbase = r0 + lq*4;
    const int b  = rbase / N_;
    const int nb = rbase % N_;
    #pragma unroll
    for (int ct=0;ct<4;++ct){
        const int f = fb + ct*16 + lane16;
        const float bv = bias[h*FO + f];
        u16* o = outN + (((size_t)(b*4+h))*N_ + nb)*FO + f;
        #pragma unroll
        for (int reg=0;reg<4;++reg){
            float x = acc[ct][reg] + bv;
            o[(size_t)reg*FO] = f2b(x>0.f ? x : 0.f);
        }
    }
}

// =====================================================================
// proj_fi: all six FI projections batched. Per-slot row-major and/or
// transposed output. grid (500, 4 h, 6 slot), block 64
// =====================================================================
struct ProjFI { const u16* WT[6]; const float* bias[6]; u16* outN[6]; u16* outT[6]; };
__global__ __launch_bounds__(64) void proj_fi(const u16* __restrict__ codeB, ProjFI a)
{
    const int slot = blockIdx.z;
    const u16* WT = a.WT[slot];
    const float* bias = a.bias[slot];
    u16* outN = a.outN[slot];
    u16* outT = a.outT[slot];

    const int l = threadIdx.x, lane16 = l&15, lq = l>>4;
    const int r0 = blockIdx.x*16;
    const int h = blockIdx.y;
    const u16* aptr = codeB + (size_t)(r0+lane16)*D_ + lq*8;
    const u16* bp[4];
    #pragma unroll
    for (int ct=0; ct<4; ++ct)
        bp[ct] = WT + ((size_t)h*FI + ct*16 + lane16)*D_ + lq*8;

    f4 acc[4] = {};
    for (int k0=0;k0<D_;k0+=32){
        bf8 av = ldb8(aptr+k0);
        #pragma unroll
        for (int ct=0;ct<4;++ct)
            acc[ct] = MFMA(av, ldb8(bp[ct]+k0), acc[ct]);
    }
    const int rbase = r0 + lq*4;
    const int b  = rbase / N_;
    const int nb = rbase % N_;
    #pragma unroll
    for (int ct=0;ct<4;++ct){
        const int f = ct*16 + lane16;
        const float bv = bias[h*FI + f];
        float v[4];
        #pragma unroll
        for (int reg=0;reg<4;++reg){
            float x = acc[ct][reg] + bv;
            v[reg] = x>0.f ? x : 0.f;
        }
        if (outN){
            u16* o = outN + (((size_t)(b*4+h))*N_ + nb)*FI + f;
            #pragma unroll
            for (int reg=0;reg<4;++reg) o[(size_t)reg*FI] = f2b(v[reg]);
        }
        if (outT){
            ushort4 o4; o4.x=f2b(v[0]); o4.y=f2b(v[1]); o4.z=f2b(v[2]); o4.w=f2b(v[3]);
            *(ushort4*)&outT[(((size_t)(b*4+h))*FI + f)*NP + nb] = o4;
        }
    }
}

// =====================================================================
// ms_mfma: maxscT[b][m][n] = max_h q[bh][n][:]·k[bh][m][:]  (bf16 out)
// grid (16, 16, 8), block 64
// =====================================================================
__global__ __launch_bounds__(64) void ms_mfma(const u16* __restrict__ q,
                                              const u16* __restrict__ k,
                                              u16* __restrict__ maxscT)
{
    const int l=threadIdx.x, lane16=l&15, lq=l>>4;
    const int b=blockIdx.x, n0=blockIdx.y*32, m0=blockIdx.z*64;
    f4 best[2][4];
    #pragma unroll
    for(int rt=0;rt<2;++rt)
        #pragma unroll
        for(int ct=0;ct<4;++ct)
            #pragma unroll
            for(int i=0;i<4;++i) best[rt][ct][i] = -FLT_MAX;

    for (int h=0;h<4;++h){
        const size_t base = ((size_t)(b*4+h))*N_*FO;
        const u16 *ap[2], *bpp[4];
        #pragma unroll
        for(int rt=0;rt<2;++rt){ int n=n0+rt*16+lane16; if(n>N_-1)n=N_-1; ap[rt]=q+base+(size_t)n*FO+lq*8; }
        #pragma unroll
        for(int ct=0;ct<4;++ct){ int m=m0+ct*16+lane16; if(m>N_-1)m=N_-1; bpp[ct]=k+base+(size_t)m*FO+lq*8; }
        f4 acc[2][4] = {};
        #pragma unroll
        for (int k0=0;k0<FO;k0+=32){
            bf8 a0=ldb8(ap[0]+k0), a1=ldb8(ap[1]+k0);
            #pragma unroll
            for(int ct=0;ct<4;++ct){
                bf8 bb=ldb8(bpp[ct]+k0);
                acc[0][ct]=MFMA(a0,bb,acc[0][ct]);
                acc[1][ct]=MFMA(a1,bb,acc[1][ct]);
            }
        }
        #pragma unroll
        for(int rt=0;rt<2;++rt)
            #pragma unroll
            for(int ct=0;ct<4;++ct)
                #pragma unroll
                for(int i=0;i<4;++i) best[rt][ct][i] = fmaxf(best[rt][ct][i], acc[rt][ct][i]);
    }
    #pragma unroll
    for(int rt=0;rt<2;++rt)
        #pragma unroll
        for(int ct=0;ct<4;++ct){
            const int m = m0+ct*16+lane16;
            const int nb = n0+rt*16+lq*4;
            ushort4 o; o.x=f2b(best[rt][ct][0]); o.y=f2b(best[rt][ct][1]);
            o.z=f2b(best[rt][ct][2]); o.w=f2b(best[rt][ct][3]);
            *(ushort4*)&maxscT[((size_t)b*NP+m)*NP + nb] = o;
        }
}

// =====================================================================
// saoo: fused  sAm = sent ⊙ (sent @ maxscT)  then  out_ori = sAm @ code
// grid (16 b, 8 stile16), block 512 (8 waves).
// Phase1: wave w computes sAm m-chunk w into LDS. Phase2: wave w computes
// out d-chunk w reading LDS sAm + codeT.
// =====================================================================
__global__ __launch_bounds__(512) void saoo(const u16* __restrict__ sentB,
                                            const u16* __restrict__ maxscT,
                                            const u16* __restrict__ codeT,
                                            float* __restrict__ out)
{
    __shared__ u16 sAmS[16][520];
    const int b=blockIdx.x, s0=blockIdx.y*16;
    const int t=threadIdx.x, w=t>>6, l=t&63, lane16=l&15, lq=l>>4;

    { // phase 1: m-chunk w
        const int m0 = w*64;
        const u16* ap = sentB + ((size_t)b*S_ + s0+lane16)*NP + lq*8;
        const u16* bp[4];
        #pragma unroll
        for(int ct=0;ct<4;++ct) bp[ct] = maxscT + ((size_t)b*NP + m0+ct*16+lane16)*NP + lq*8;
        f4 acc[4] = {};
        for (int k0=0;k0<NP;k0+=32){
            bf8 av=ldb8(ap+k0);
            #pragma unroll
            for(int ct=0;ct<4;++ct) acc[ct]=MFMA(av, ldb8(bp[ct]+k0), acc[ct]);
        }
        #pragma unroll
        for(int ct=0;ct<4;++ct){
            const int m = m0+ct*16+lane16;
            #pragma unroll
            for(int reg=0;reg<4;++reg){
                const int s = s0+lq*4+reg;
                const float sv = b2f(sentB[((size_t)b*S_+s)*NP+m]);
                sAmS[lq*4+reg][m] = f2b(acc[ct][reg]*sv);
            }
        }
    }
    __syncthreads();
    { // phase 2: d-chunk w
        const int d0 = w*64;
        const u16* bp[4];
        #pragma unroll
        for(int ct=0;ct<4;++ct) bp[ct] = codeT + ((size_t)b*D_ + d0+ct*16+lane16)*NP + lq*8;
        f4 acc[4] = {};
        for (int k0=0;k0<NP;k0+=32){
            bf8 av = *(const bf8*)&sAmS[lane16][k0+lq*8];
            #pragma unroll
            for(int ct=0;ct<4;++ct) acc[ct]=MFMA(av, ldb8(bp[ct]+k0), acc[ct]);
        }
        #pragma unroll
        for(int ct=0;ct<4;++ct){
            const int d = d0+ct*16+lane16;
            #pragma unroll
            for(int reg=0;reg<4;++reg){
                const int s = s0+lq*4+reg;
                out[((size_t)b*S_+s)*1024 + d] = acc[ct][reg];
            }
        }
    }
}

// =====================================================================
// attn_fused: qs (k-split across waves, LDS reduce) + attention
// (m-split across waves, LDS reduce), both branches in one launch.
// grid (64 bh, 4 stile32, 2 branch), block 256 (4 waves).
// =====================================================================
struct AttnArgs { const u16* qT[2]; const u16* kp[2]; const u16* vT[2]; };
__global__ __launch_bounds__(256) void attn_fused(AttnArgs a,
                                                  const u16* __restrict__ sentB,
                                                  const float* __restrict__ inc,
                                                  float* __restrict__ out)
{
    __shared__ float red[4][32][68];   // 34.8 KB partials (qs then O)
    __shared__ u16 qsS[32][72];        // 4.6 KB
    __shared__ u16 Pw[4][32][72];      // 18.4 KB per-wave P tiles
    const int bh=blockIdx.x, b=bh>>2, h=bh&3, s0=blockIdx.y*32, br=blockIdx.z;
    const u16* qT = a.qT[br];
    const u16* kp = a.kp[br];
    const u16* vT = a.vT[br];
    const int t=threadIdx.x, w=t>>6, l=t&63, lane16=l&15, lq=l>>4;

    { // phase 1: qs partial, k-range [w*128, w*128+128)
        const u16 *ap[2], *bp[4];
        #pragma unroll
        for(int rt=0;rt<2;++rt) ap[rt] = sentB + ((size_t)b*S_ + s0+rt*16+lane16)*NP + w*128 + lq*8;
        #pragma unroll
        for(int ct=0;ct<4;++ct) bp[ct] = qT + ((size_t)bh*FI + ct*16+lane16)*NP + w*128 + lq*8;
        f4 acc[2][4] = {};
        #pragma unroll
        for (int k0=0;k0<128;k0+=32){
            bf8 a0=ldb8(ap[0]+k0), a1=ldb8(ap[1]+k0);
            #pragma unroll
            for(int ct=0;ct<4;++ct){
                bf8 bb=ldb8(bp[ct]+k0);
                acc[0][ct]=MFMA(a0,bb,acc[0][ct]);
                acc[1][ct]=MFMA(a1,bb,acc[1][ct]);
            }
        }
        #pragma unroll
        for(int rt=0;rt<2;++rt)
            #pragma unroll
            for(int ct=0;ct<4;++ct)
                #pragma unroll
                for(int reg=0;reg<4;++reg)
                    red[w][rt*16+lq*4+reg][ct*16+lane16] = acc[rt][ct][reg];
    }
    __syncthreads();
    { // reduce 4 k-partials -> qs bf16
        const int s=t>>3, f0=(t&7)*8;
        #pragma unroll
        for (int j=0;j<8;++j){
            float v = red[0][s][f0+j]+red[1][s][f0+j]+red[2][s][f0+j]+red[3][s][f0+j];
            qsS[s][f0+j] = f2b(v);
        }
    }
    __syncthreads();

    // phase 2: attention, wave w handles m0 = w*64 and w*64+256
    f4 accO[2][4] = {};
    #pragma unroll
    for (int c=0;c<2;++c){
        const int m0 = w*64 + c*256;
        f4 p[2][4] = {};
        const u16* bp[4];
        #pragma unroll
        for(int ct=0;ct<4;++ct){
            int m=m0+ct*16+lane16; if(m>N_-1)m=N_-1;
            bp[ct] = kp + ((size_t)bh*N_+m)*FI + lq*8;
        }
        #pragma unroll
        for (int kk=0; kk<FI; kk+=32){
            bf8 a0 = *(const bf8*)&qsS[lane16][kk+lq*8];
            bf8 a1 = *(const bf8*)&qsS[16+lane16][kk+lq*8];
            #pragma unroll
            for(int ct=0;ct<4;++ct){
                bf8 bb=ldb8(bp[ct]+kk);
                p[0][ct]=MFMA(a0,bb,p[0][ct]);
                p[1][ct]=MFMA(a1,bb,p[1][ct]);
            }
        }
        // weight by sentence mask, store bf16 P tile (per-wave buffer)
        #pragma unroll
        for(int rt=0;rt<2;++rt)
            #pragma unroll
            for(int ct=0;ct<4;++ct){
                const int m = m0+ct*16+lane16;
                #pragma unroll
                for(int reg=0;reg<4;++reg){
                    const int s = s0+rt*16+lq*4+reg;
                    const float sv = b2f(sentB[((size_t)b*S_+s)*NP+m]);
                    const float wgt = br ? ((m<N_)? sv-1.f : 0.f) : sv;
                    Pw[w][rt*16+lq*4+reg][ct*16+lane16] = f2b(p[rt][ct][reg]*wgt);
                }
            }
        // PV for this chunk
        #pragma unroll
        for (int kk2=0; kk2<64; kk2+=32){
            bf8 a2[2];
            #pragma unroll
            for(int rt=0;rt<2;++rt) a2[rt] = *(const bf8*)&Pw[w][rt*16+lane16][kk2+lq*8];
            #pragma unroll
            for(int ct=0;ct<4;++ct){
                bf8 vv = ldb8(vT + ((size_t)bh*FI + ct*16+lane16)*NP + m0+kk2+lq*8);
                accO[0][ct]=MFMA(a2[0],vv,accO[0][ct]);
                accO[1][ct]=MFMA(a2[1],vv,accO[1][ct]);
            }
        }
    }
    // phase 3: reduce 4 m-partials of O, apply fac, write out
    #pragma unroll
    for(int rt=0;rt<2;++rt)
        #pragma unroll
        for(int ct=0;ct<4;++ct)
            #pragma unroll
            for(int reg=0;reg<4;++reg)
                red[w][rt*16+lq*4+reg][ct*16+lane16] = accO[rt][ct][reg];
    __syncthreads();
    {
        const int s=t>>3, f0=(t&7)*8;
        float fac = 1.f;
        if (br){ const float ic = inc[b*S_+s0+s]; fac = ic/(500.f-ic); }
        const size_t o = ((size_t)b*S_+s0+s)*1024 + (br?768:512) + h*FI + f0;
        #pragma unroll
        for (int j=0;j<8;++j){
            float v = red[0][s][f0+j]+red[1][s][f0+j]+red[2][s][f0+j]+red[3][s][f0+j];
            out[o+j] = v*fac;
        }
    }
}

// =====================================================================
extern "C" void kernel_launch(void* const* d_in, const int* in_sizes, int n_in,
                              void* d_out, int out_size, void* d_ws, size_t ws_size,
                              hipStream_t stream)
{
    const float* code   = (const float*)d_in[0];
    const float* sent   = (const float*)d_in[1];
    const float* Wq_ori = (const float*)d_in[2];
    const float* bq_ori = (const float*)d_in[3];
    const float* Wk_ori = (const float*)d_in[4];
    const float* bk_ori = (const float*)d_in[5];
    const float* Wq_in  = (const float*)d_in[6];
    const float* bq_in  = (const float*)d_in[7];
    const float* Wk_in  = (const float*)d_in[8];
    const float* bk_in  = (const float*)d_in[9];
    const float* Wv_in  = (const float*)d_in[10];
    const float* bv_in  = (const float*)d_in[11];
    const float* Wq_out = (const float*)d_in[12];
    const float* bq_out = (const float*)d_in[13];
    const float* Wk_out = (const float*)d_in[14];
    const float* bk_out = (const float*)d_in[15];
    const float* Wv_out = (const float*)d_in[16];
    const float* bv_out = (const float*)d_in[17];
    float* out = (float*)d_out;

    char* w = (char*)d_ws;
    u16*   codeB  = (u16*)(w);                  // 8,192,000 B
    u16*   WTqo   = (u16*)(w + 8192000);        // 524,288
    u16*   WTko   = (u16*)(w + 8716288);        // 524,288
    u16*   WTqi   = (u16*)(w + 9240576);        // 262,144 each
    u16*   WTki   = (u16*)(w + 9502720);
    u16*   WTvi   = (u16*)(w + 9764864);
    u16*   WTqu   = (u16*)(w + 10027008);
    u16*   WTku   = (u16*)(w + 10289152);
    u16*   WTvu   = (u16*)(w + 10551296);
    u16*   sentB  = (u16*)(w + 10813440);       // 2,097,152
    float* incp   = (float*)(w + 12910592);     // 8,192
    char*  S      = w + 12918784;
    // phase B (ori scratch)
    u16* q_ori  = (u16*)(S);                    // 8,192,000
    u16* k_ori  = (u16*)(S + 8192000);          // 8,192,000
    u16* maxscT = (u16*)(S + 16384000);         // 8,388,608
    u16* codeT  = (u16*)(S + 24772608);         // 8,388,608 (peak ~46.1 MB)
    // phase C overlay (dead after saoo)
    u16* k_in   = (u16*)(S);                    // 4,096,000
    u16* k_out  = (u16*)(S + 4096000);          // 4,096,000
    u16* qT_in  = (u16*)(S + 8192000);          // 4,194,304 each
    u16* qT_out = (u16*)(S + 12386304);
    u16* vT_in  = (u16*)(S + 16580608);
    u16* vT_out = (u16*)(S + 20774912);         // ends S+24,969,216

    // ---- prep ----
    prep_code<<<dim3(16,8,8), 256, 0, stream>>>(code, codeB, codeT);
    prep_sent<<<dim3(16,128), 128, 0, stream>>>(sent, sentB, incp);
    PWAll pw;
    pw.W[0]=Wq_ori; pw.W[1]=Wk_ori; pw.W[2]=Wq_in; pw.W[3]=Wk_in;
    pw.W[4]=Wv_in;  pw.W[5]=Wq_out; pw.W[6]=Wk_out; pw.W[7]=Wv_out;
    pw.WT[0]=WTqo; pw.WT[1]=WTko; pw.WT[2]=WTqi; pw.WT[3]=WTki;
    pw.WT[4]=WTvi; pw.WT[5]=WTqu; pw.WT[6]=WTku; pw.WT[7]=WTvu;
    prep_w_all<<<dim3(4,10,8), 256, 0, stream>>>(pw);

    // ---- ori branch ----
    ProjFO pfo;
    pfo.WT[0]=WTqo; pfo.WT[1]=WTko;
    pfo.bias[0]=bq_ori; pfo.bias[1]=bk_ori;
    pfo.outN[0]=q_ori; pfo.outN[1]=k_ori;
    proj_fo<<<dim3(500,8,2), 64, 0, stream>>>(codeB, pfo);
    ms_mfma<<<dim3(16,16,8), 64, 0, stream>>>(q_ori, k_ori, maxscT);
    saoo<<<dim3(16,8), 512, 0, stream>>>(sentB, maxscT, codeT, out);

    // ---- in/out branch (ori scratch now dead; overlay) ----
    zero_pad4<<<dim3(64,4), 256, 0, stream>>>(qT_in, qT_out, vT_in, vT_out);
    ProjFI pfi;
    pfi.WT[0]=WTqi; pfi.WT[1]=WTki; pfi.WT[2]=WTvi;
    pfi.WT[3]=WTqu; pfi.WT[4]=WTku; pfi.WT[5]=WTvu;
    pfi.bias[0]=bq_in; pfi.bias[1]=bk_in; pfi.bias[2]=bv_in;
    pfi.bias[3]=bq_out; pfi.bias[4]=bk_out; pfi.bias[5]=bv_out;
    pfi.outN[0]=nullptr; pfi.outN[1]=k_in;  pfi.outN[2]=nullptr;
    pfi.outN[3]=nullptr; pfi.outN[4]=k_out; pfi.outN[5]=nullptr;
    pfi.outT[0]=qT_in;  pfi.outT[1]=nullptr; pfi.outT[2]=vT_in;
    pfi.outT[3]=qT_out; pfi.outT[4]=nullptr; pfi.outT[5]=vT_out;
    proj_fi<<<dim3(500,4,6), 64, 0, stream>>>(codeB, pfi);

    AttnArgs aa;
    aa.qT[0]=qT_in;  aa.qT[1]=qT_out;
    aa.kp[0]=k_in;   aa.kp[1]=k_out;
    aa.vT[0]=vT_in;  aa.vT[1]=vT_out;
    attn_fused<<<dim3(64,4,2), 256, 0, stream>>>(aa, sentB, incp, out);
}

// Round 4
// 136.384 us; speedup vs baseline: 5.7663x; 2.0852x over previous
//
#include <hip/hip_runtime.h>
#include <cfloat>

#define B_  16
#define N_  500   // INPUT_SIZE
#define NP  512   // padded N
#define S_  128   // SENTENCE_SIZE
#define D_  512
#define FO  128   // ori head dim
#define FI  64    // in/out head dim

typedef unsigned short u16;
typedef __attribute__((ext_vector_type(8))) short bf8;
typedef __attribute__((ext_vector_type(4))) float f4;

#define MFMA(a,b,c) __builtin_amdgcn_mfma_f32_16x16x32_bf16((a),(b),(c),0,0,0)

__device__ __forceinline__ u16 f2b(float x){
    union{float f;unsigned u;} v; v.f=x;
    unsigned r = v.u + 0x7fffu + ((v.u>>16)&1u);
    return (u16)(r>>16);
}
__device__ __forceinline__ float b2f(u16 x){
    union{unsigned u;float f;} v; v.u=((unsigned)x)<<16; return v.f;
}
__device__ __forceinline__ bf8 ldb8(const u16* p){ return *(const bf8*)p; }

// =====================================================================
// prep_code: codeB[b][m][d] bf16 (m<500) and codeT[b][d][mP] bf16 (pad 0)
// grid (16, 8 mtile, 8 dtile), block 256
// =====================================================================
__global__ __launch_bounds__(256) void prep_code(const float* __restrict__ code,
                                                 u16* __restrict__ codeB,
                                                 u16* __restrict__ codeT)
{
    __shared__ float T[64][65];
    const int b = blockIdx.x, m0 = blockIdx.y*64, d0 = blockIdx.z*64;
    const int t = threadIdx.x;
    #pragma unroll
    for (int i=0;i<16;++i){
        int idx = t + i*256; int rr = idx>>6, cc = idx&63;
        int m = m0+rr;
        T[rr][cc] = (m < N_) ? code[((size_t)b*N_+m)*D_ + d0+cc] : 0.f;
    }
    __syncthreads();
    #pragma unroll
    for (int i=0;i<16;++i){
        int idx=t+i*256; int rr=idx>>6, cc=idx&63; int m=m0+rr;
        if (m<N_) codeB[((size_t)b*N_+m)*D_ + d0+cc] = f2b(T[rr][cc]);
    }
    #pragma unroll
    for (int i=0;i<16;++i){
        int idx=t+i*256; int dd=idx>>6, mm=idx&63;
        codeT[((size_t)b*D_ + d0+dd)*NP + m0+mm] = f2b(T[mm][dd]);
    }
}

// =====================================================================
// prep_sent: sentB[b][s][nP] bf16 (pad 0) + inc[b][s] = sum_n sent
// =====================================================================
__global__ __launch_bounds__(128) void prep_sent(const float* __restrict__ sent,
                                                 u16* __restrict__ sentB,
                                                 float* __restrict__ inc)
{
    const int b=blockIdx.x, s=blockIdx.y, t=threadIdx.x;
    const float* row = sent + ((size_t)b*S_+s)*N_;
    float4 v = make_float4(0.f,0.f,0.f,0.f);
    const int n = t*4;
    if (n < N_) v = *(const float4*)(row+n);
    float sum = v.x+v.y+v.z+v.w;
    ushort4 o; o.x=f2b(v.x); o.y=f2b(v.y); o.z=f2b(v.z); o.w=f2b(v.w);
    *(ushort4*)&sentB[((size_t)b*S_+s)*NP + n] = o;
    #pragma unroll
    for (int off=32; off; off>>=1) sum += __shfl_down(sum, off);
    __shared__ float ls[2];
    if ((t&63)==0) ls[t>>6]=sum;
    __syncthreads();
    if (t==0) inc[b*S_+s] = ls[0]+ls[1];
}

// =====================================================================
// prep_w_all: all 8 weight transposes into contiguous WallT.
// =====================================================================
struct PWAll { const float* W[8]; u16* WT[8]; };
__global__ __launch_bounds__(256) void prep_w_all(PWAll a)
{
    const int slot = blockIdx.y;
    const int widx = slot<4 ? (slot>>1) : slot-2;
    const int ftile= slot<4 ? (slot&1)  : 0;
    const int F    = slot<4 ? 128 : 64;
    const float* W = a.W[widx];
    u16* WT        = a.WT[widx];
    __shared__ float T[64][65];
    const int h=blockIdx.x, f0=ftile*64, d0=blockIdx.z*64, t=threadIdx.x;
    #pragma unroll
    for (int i=0;i<16;++i){
        int idx=t+i*256; int rr=idx>>6, cc=idx&63;
        T[rr][cc] = W[((size_t)h*D_ + d0+rr)*F + f0+cc];
    }
    __syncthreads();
    #pragma unroll
    for (int i=0;i<16;++i){
        int idx=t+i*256; int ff=idx>>6, dd=idx&63;
        WT[((size_t)h*F + f0+ff)*D_ + d0+dd] = f2b(T[dd][ff]);
    }
}

// zero pad cols n in [500,512) of 4 arrays laid out [64bh][64f][512]
__global__ __launch_bounds__(256) void zero_pad4(u16* a0, u16* a1, u16* a2, u16* a3)
{
    u16* arr4[4] = {a0,a1,a2,a3};
    u16* base = arr4[blockIdx.y] + (size_t)blockIdx.x*FI*NP;
    for (int idx=threadIdx.x; idx<FI*12; idx+=256){
        int f = idx/12, n = N_ + idx%12;
        base[(size_t)f*NP + n] = 0;
    }
}

// =====================================================================
// proj_gemm: C[8064 x 2560] = codeB @ WallT^T, K=512, bias+relu epilogue
// with per-region store layout.  128x128 tile, 4 waves, LDS dbuf, BK=32.
// Regions (col c): 0:q_ori 1:k_ori | 2:q_in 3:k_in 4:v_in 5:q_out 6:k_out 7:v_out
// grid (63, ntiles), block 256.  ctile0 selects col range.
// =====================================================================
struct GemmOut { const float* bias[8]; u16* dst[8]; };
__global__ __launch_bounds__(256) void proj_gemm(const u16* __restrict__ codeB,
                                                 const u16* __restrict__ WallT,
                                                 GemmOut go, int ctile0)
{
    __shared__ alignas(16) u16 As[2][128*32];
    __shared__ alignas(16) u16 Bs[2][128*32];
    const int t = threadIdx.x;
    const int w = t>>6, l = t&63, lane16 = l&15, lq = l>>4;
    const int r0 = blockIdx.x*128;
    const int c0 = (blockIdx.y + ctile0)*128;
    const int wr = (w>>1)*64, wc = (w&1)*64;
    const int srow = t>>2, skc = (t&3)*8;     // staging: 2 rows x 16B per thread per tile

    f4 acc[4][4] = {};
    // prologue: stage k0=0
    #pragma unroll
    for (int i=0;i<2;++i){
        const int row = srow + i*64;
        *(bf8*)&As[0][row*32 + skc] = ldb8(codeB + (size_t)(r0+row)*D_ + skc);
        *(bf8*)&Bs[0][row*32 + skc] = ldb8(WallT + (size_t)(c0+row)*D_ + skc);
    }
    __syncthreads();
    int buf = 0;
    for (int k0=0; k0<D_; k0+=32){
        const bool more = (k0+32) < D_;
        bf8 pa[2], pb[2];
        if (more){
            #pragma unroll
            for (int i=0;i<2;++i){
                const int row = srow + i*64;
                pa[i] = ldb8(codeB + (size_t)(r0+row)*D_ + k0+32 + skc);
                pb[i] = ldb8(WallT + (size_t)(c0+row)*D_ + k0+32 + skc);
            }
        }
        bf8 af[4], bfr[4];
        #pragma unroll
        for (int i=0;i<4;++i){
            af[i]  = *(const bf8*)&As[buf][(wr + i*16 + lane16)*32 + lq*8];
            bfr[i] = *(const bf8*)&Bs[buf][(wc + i*16 + lane16)*32 + lq*8];
        }
        #pragma unroll
        for (int i=0;i<4;++i)
            #pragma unroll
            for (int j=0;j<4;++j)
                acc[i][j] = MFMA(af[i], bfr[j], acc[i][j]);
        if (more){
            #pragma unroll
            for (int i=0;i<2;++i){
                const int row = srow + i*64;
                *(bf8*)&As[buf^1][row*32+skc] = pa[i];
                *(bf8*)&Bs[buf^1][row*32+skc] = pb[i];
            }
            __syncthreads();
            buf ^= 1;
        }
    }
    // epilogue
    #pragma unroll
    for (int j=0;j<4;++j){
        const int c = c0 + wc + j*16 + lane16;
        int ri, hf, F;
        if (c < 1024){ ri = c>>9; hf = c & 511; F = 128; }
        else { const int u = c-1024; ri = 2 + (u>>8); hf = u & 255; F = 64; }
        const float bv = go.bias[ri][hf];
        const int h  = (F==128) ? (hf>>7) : (hf>>6);
        const int f2 = hf & (F-1);
        const bool tr = (ri>=2) && (ri!=3) && (ri!=6);
        #pragma unroll
        for (int i=0;i<4;++i){
            const int rb = r0 + wr + i*16 + lq*4;
            if (rb >= 8000) continue;
            const int b  = rb / 500;
            const int n0 = rb % 500;
            float v[4];
            #pragma unroll
            for (int reg=0;reg<4;++reg){
                float x = acc[i][j][reg] + bv;
                v[reg] = x>0.f ? x : 0.f;
            }
            if (tr){
                ushort4 o4; o4.x=f2b(v[0]); o4.y=f2b(v[1]); o4.z=f2b(v[2]); o4.w=f2b(v[3]);
                *(ushort4*)&go.dst[ri][((size_t)(b*4+h)*FI + f2)*NP + n0] = o4;
            } else {
                u16* o = go.dst[ri] + ((size_t)(b*4+h)*N_ + n0)*F + f2;
                #pragma unroll
                for (int reg=0;reg<4;++reg) o[(size_t)reg*F] = f2b(v[reg]);
            }
        }
    }
}

// =====================================================================
// ms_mfma: maxscT[b][m][n] = max_h q[bh][n][:]·k[bh][m][:]  (bf16 out)
// 4-wave blocks, LDS-staged Q(64n)/K(128m) tiles, K=128 per head.
// grid (16, 8 ntile64, 4 mtile128), block 256
// =====================================================================
__global__ __launch_bounds__(256) void ms_mfma(const u16* __restrict__ q,
                                               const u16* __restrict__ k,
                                               u16* __restrict__ maxscT)
{
    __shared__ alignas(16) u16 Qs[64][136];
    __shared__ alignas(16) u16 Ks[128][136];
    const int t=threadIdx.x, w=t>>6, l=t&63, lane16=l&15, lq=l>>4;
    const int b=blockIdx.x, n0=blockIdx.y*64, m0=blockIdx.z*128;
    const int wr=(w>>1)*32, wc=(w&1)*64;

    f4 best[2][4];
    #pragma unroll
    for(int rt=0;rt<2;++rt)
        #pragma unroll
        for(int ct=0;ct<4;++ct)
            #pragma unroll
            for(int i=0;i<4;++i) best[rt][ct][i] = -FLT_MAX;

    for (int h=0;h<4;++h){
        const u16* qh = q + (size_t)(b*4+h)*N_*FO;
        const u16* kh = k + (size_t)(b*4+h)*N_*FO;
        #pragma unroll
        for (int i=0;i<4;++i){
            const int e=t+i*256, row=e>>4, kc=(e&15)*8;
            int n=n0+row; if(n>N_-1)n=N_-1;
            *(bf8*)&Qs[row][kc] = ldb8(qh + (size_t)n*FO + kc);
        }
        #pragma unroll
        for (int i=0;i<8;++i){
            const int e=t+i*256, row=e>>4, kc=(e&15)*8;
            int m=m0+row; if(m>N_-1)m=N_-1;
            *(bf8*)&Ks[row][kc] = ldb8(kh + (size_t)m*FO + kc);
        }
        __syncthreads();
        f4 acc[2][4]={};
        #pragma unroll
        for (int kk=0;kk<FO;kk+=32){
            bf8 a0=*(const bf8*)&Qs[wr+lane16][kk+lq*8];
            bf8 a1=*(const bf8*)&Qs[wr+16+lane16][kk+lq*8];
            #pragma unroll
            for(int ct=0;ct<4;++ct){
                bf8 bb=*(const bf8*)&Ks[wc+ct*16+lane16][kk+lq*8];
                acc[0][ct]=MFMA(a0,bb,acc[0][ct]);
                acc[1][ct]=MFMA(a1,bb,acc[1][ct]);
            }
        }
        #pragma unroll
        for(int rt=0;rt<2;++rt)
            #pragma unroll
            for(int ct=0;ct<4;++ct)
                #pragma unroll
                for(int i=0;i<4;++i) best[rt][ct][i] = fmaxf(best[rt][ct][i], acc[rt][ct][i]);
        __syncthreads();
    }
    #pragma unroll
    for(int rt=0;rt<2;++rt)
        #pragma unroll
        for(int ct=0;ct<4;++ct){
            const int m  = m0+wc+ct*16+lane16;
            const int nb = n0+wr+rt*16+lq*4;
            if (m < N_ && nb < N_){
                ushort4 o; o.x=f2b(best[rt][ct][0]); o.y=f2b(best[rt][ct][1]);
                o.z=f2b(best[rt][ct][2]); o.w=f2b(best[rt][ct][3]);
                *(ushort4*)&maxscT[((size_t)b*NP+m)*NP + nb] = o;
            }
        }
}

// =====================================================================
// saoo: fused  sAm = sent ⊙ (sent @ maxscT)  then  out_ori = sAm @ code
// grid (16 b, 8 stile16), block 512 (8 waves).
// =====================================================================
__global__ __launch_bounds__(512) void saoo(const u16* __restrict__ sentB,
                                            const u16* __restrict__ maxscT,
                                            const u16* __restrict__ codeT,
                                            float* __restrict__ out)
{
    __shared__ u16 sAmS[16][520];
    const int b=blockIdx.x, s0=blockIdx.y*16;
    const int t=threadIdx.x, w=t>>6, l=t&63, lane16=l&15, lq=l>>4;

    { // phase 1: m-chunk w
        const int m0 = w*64;
        const u16* ap = sentB + ((size_t)b*S_ + s0+lane16)*NP + lq*8;
        const u16* bp[4];
        #pragma unroll
        for(int ct=0;ct<4;++ct) bp[ct] = maxscT + ((size_t)b*NP + m0+ct*16+lane16)*NP + lq*8;
        f4 acc[4] = {};
        for (int k0=0;k0<NP;k0+=32){
            bf8 av=ldb8(ap+k0);
            #pragma unroll
            for(int ct=0;ct<4;++ct) acc[ct]=MFMA(av, ldb8(bp[ct]+k0), acc[ct]);
        }
        #pragma unroll
        for(int ct=0;ct<4;++ct){
            const int m = m0+ct*16+lane16;
            #pragma unroll
            for(int reg=0;reg<4;++reg){
                const int s = s0+lq*4+reg;
                const float sv = b2f(sentB[((size_t)b*S_+s)*NP+m]);
                sAmS[lq*4+reg][m] = f2b(acc[ct][reg]*sv);
            }
        }
    }
    __syncthreads();
    { // phase 2: d-chunk w
        const int d0 = w*64;
        const u16* bp[4];
        #pragma unroll
        for(int ct=0;ct<4;++ct) bp[ct] = codeT + ((size_t)b*D_ + d0+ct*16+lane16)*NP + lq*8;
        f4 acc[4] = {};
        for (int k0=0;k0<NP;k0+=32){
            bf8 av = *(const bf8*)&sAmS[lane16][k0+lq*8];
            #pragma unroll
            for(int ct=0;ct<4;++ct) acc[ct]=MFMA(av, ldb8(bp[ct]+k0), acc[ct]);
        }
        #pragma unroll
        for(int ct=0;ct<4;++ct){
            const int d = d0+ct*16+lane16;
            #pragma unroll
            for(int reg=0;reg<4;++reg){
                const int s = s0+lq*4+reg;
                out[((size_t)b*S_+s)*1024 + d] = acc[ct][reg];
            }
        }
    }
}

// =====================================================================
// attn_fused: qs (k-split across waves, LDS reduce) + attention
// (m-split across waves, LDS reduce), both branches in one launch.
// grid (64 bh, 4 stile32, 2 branch), block 256 (4 waves).
// =====================================================================
struct AttnArgs { const u16* qT[2]; const u16* kp[2]; const u16* vT[2]; };
__global__ __launch_bounds__(256) void attn_fused(AttnArgs a,
                                                  const u16* __restrict__ sentB,
                                                  const float* __restrict__ inc,
                                                  float* __restrict__ out)
{
    __shared__ float red[4][32][68];
    __shared__ u16 qsS[32][72];
    __shared__ u16 Pw[4][32][72];
    const int bh=blockIdx.x, b=bh>>2, h=bh&3, s0=blockIdx.y*32, br=blockIdx.z;
    const u16* qT = a.qT[br];
    const u16* kp = a.kp[br];
    const u16* vT = a.vT[br];
    const int t=threadIdx.x, w=t>>6, l=t&63, lane16=l&15, lq=l>>4;

    { // phase 1: qs partial, k-range [w*128, w*128+128)
        const u16 *ap[2], *bp[4];
        #pragma unroll
        for(int rt=0;rt<2;++rt) ap[rt] = sentB + ((size_t)b*S_ + s0+rt*16+lane16)*NP + w*128 + lq*8;
        #pragma unroll
        for(int ct=0;ct<4;++ct) bp[ct] = qT + ((size_t)bh*FI + ct*16+lane16)*NP + w*128 + lq*8;
        f4 acc[2][4] = {};
        #pragma unroll
        for (int k0=0;k0<128;k0+=32){
            bf8 a0=ldb8(ap[0]+k0), a1=ldb8(ap[1]+k0);
            #pragma unroll
            for(int ct=0;ct<4;++ct){
                bf8 bb=ldb8(bp[ct]+k0);
                acc[0][ct]=MFMA(a0,bb,acc[0][ct]);
                acc[1][ct]=MFMA(a1,bb,acc[1][ct]);
            }
        }
        #pragma unroll
        for(int rt=0;rt<2;++rt)
            #pragma unroll
            for(int ct=0;ct<4;++ct)
                #pragma unroll
                for(int reg=0;reg<4;++reg)
                    red[w][rt*16+lq*4+reg][ct*16+lane16] = acc[rt][ct][reg];
    }
    __syncthreads();
    {
        const int s=t>>3, f0=(t&7)*8;
        #pragma unroll
        for (int j=0;j<8;++j){
            float v = red[0][s][f0+j]+red[1][s][f0+j]+red[2][s][f0+j]+red[3][s][f0+j];
            qsS[s][f0+j] = f2b(v);
        }
    }
    __syncthreads();

    f4 accO[2][4] = {};
    #pragma unroll
    for (int c=0;c<2;++c){
        const int m0 = w*64 + c*256;
        f4 p[2][4] = {};
        const u16* bp[4];
        #pragma unroll
        for(int ct=0;ct<4;++ct){
            int m=m0+ct*16+lane16; if(m>N_-1)m=N_-1;
            bp[ct] = kp + ((size_t)bh*N_+m)*FI + lq*8;
        }
        #pragma unroll
        for (int kk=0; kk<FI; kk+=32){
            bf8 a0 = *(const bf8*)&qsS[lane16][kk+lq*8];
            bf8 a1 = *(const bf8*)&qsS[16+lane16][kk+lq*8];
            #pragma unroll
            for(int ct=0;ct<4;++ct){
                bf8 bb=ldb8(bp[ct]+kk);
                p[0][ct]=MFMA(a0,bb,p[0][ct]);
                p[1][ct]=MFMA(a1,bb,p[1][ct]);
            }
        }
        #pragma unroll
        for(int rt=0;rt<2;++rt)
            #pragma unroll
            for(int ct=0;ct<4;++ct){
                const int m = m0+ct*16+lane16;
                #pragma unroll
                for(int reg=0;reg<4;++reg){
                    const int s = s0+rt*16+lq*4+reg;
                    const float sv = b2f(sentB[((size_t)b*S_+s)*NP+m]);
                    const float wgt = br ? ((m<N_)? sv-1.f : 0.f) : sv;
                    Pw[w][rt*16+lq*4+reg][ct*16+lane16] = f2b(p[rt][ct][reg]*wgt);
                }
            }
        #pragma unroll
        for (int kk2=0; kk2<64; kk2+=32){
            bf8 a2[2];
            #pragma unroll
            for(int rt=0;rt<2;++rt) a2[rt] = *(const bf8*)&Pw[w][rt*16+lane16][kk2+lq*8];
            #pragma unroll
            for(int ct=0;ct<4;++ct){
                bf8 vv = ldb8(vT + ((size_t)bh*FI + ct*16+lane16)*NP + m0+kk2+lq*8);
                accO[0][ct]=MFMA(a2[0],vv,accO[0][ct]);
                accO[1][ct]=MFMA(a2[1],vv,accO[1][ct]);
            }
        }
    }
    #pragma unroll
    for(int rt=0;rt<2;++rt)
        #pragma unroll
        for(int ct=0;ct<4;++ct)
            #pragma unroll
            for(int reg=0;reg<4;++reg)
                red[w][rt*16+lq*4+reg][ct*16+lane16] = accO[rt][ct][reg];
    __syncthreads();
    {
        const int s=t>>3, f0=(t&7)*8;
        float fac = 1.f;
        if (br){ const float ic = inc[b*S_+s0+s]; fac = ic/(500.f-ic); }
        const size_t o = ((size_t)b*S_+s0+s)*1024 + (br?768:512) + h*FI + f0;
        #pragma unroll
        for (int j=0;j<8;++j){
            float v = red[0][s][f0+j]+red[1][s][f0+j]+red[2][s][f0+j]+red[3][s][f0+j];
            out[o+j] = v*fac;
        }
    }
}

// =====================================================================
extern "C" void kernel_launch(void* const* d_in, const int* in_sizes, int n_in,
                              void* d_out, int out_size, void* d_ws, size_t ws_size,
                              hipStream_t stream)
{
    const float* code   = (const float*)d_in[0];
    const float* sent   = (const float*)d_in[1];
    const float* Wq_ori = (const float*)d_in[2];
    const float* bq_ori = (const float*)d_in[3];
    const float* Wk_ori = (const float*)d_in[4];
    const float* bk_ori = (const float*)d_in[5];
    const float* Wq_in  = (const float*)d_in[6];
    const float* bq_in  = (const float*)d_in[7];
    const float* Wk_in  = (const float*)d_in[8];
    const float* bk_in  = (const float*)d_in[9];
    const float* Wv_in  = (const float*)d_in[10];
    const float* bv_in  = (const float*)d_in[11];
    const float* Wq_out = (const float*)d_in[12];
    const float* bq_out = (const float*)d_in[13];
    const float* Wk_out = (const float*)d_in[14];
    const float* bk_out = (const float*)d_in[15];
    const float* Wv_out = (const float*)d_in[16];
    const float* bv_out = (const float*)d_in[17];
    float* out = (float*)d_out;

    char* w = (char*)d_ws;
    u16*   codeB  = (u16*)(w);                  // 8064*512*2 = 8,257,536 B (rows >=8000 garbage ok)
    u16*   WallT  = (u16*)(w + 8257536);        // 2560*512*2 = 2,621,440 B contiguous
    u16*   WTqo   = WallT;                      // u16 offsets
    u16*   WTko   = WallT +  262144;
    u16*   WTqi   = WallT +  524288;
    u16*   WTki   = WallT +  655360;
    u16*   WTvi   = WallT +  786432;
    u16*   WTqu   = WallT +  917504;
    u16*   WTku   = WallT + 1048576;
    u16*   WTvu   = WallT + 1179648;
    u16*   sentB  = (u16*)(w + 10878976);       // 2,097,152
    float* incp   = (float*)(w + 12976128);     // 8,192
    char*  S      = w + 12984320;
    // phase B (ori scratch)
    u16* q_ori  = (u16*)(S);                    // 8,192,000
    u16* k_ori  = (u16*)(S + 8192000);          // 8,192,000
    u16* maxscT = (u16*)(S + 16384000);         // 8,388,608
    u16* codeT  = (u16*)(S + 24772608);         // 8,388,608  (total ~46.1 MB)
    // phase C overlay (dead after saoo)
    u16* k_in   = (u16*)(S);
    u16* k_out  = (u16*)(S + 4096000);
    u16* qT_in  = (u16*)(S + 8192000);
    u16* qT_out = (u16*)(S + 12386304);
    u16* vT_in  = (u16*)(S + 16580608);
    u16* vT_out = (u16*)(S + 20774912);

    // ---- prep ----
    prep_code<<<dim3(16,8,8), 256, 0, stream>>>(code, codeB, codeT);
    prep_sent<<<dim3(16,128), 128, 0, stream>>>(sent, sentB, incp);
    PWAll pw;
    pw.W[0]=Wq_ori; pw.W[1]=Wk_ori; pw.W[2]=Wq_in; pw.W[3]=Wk_in;
    pw.W[4]=Wv_in;  pw.W[5]=Wq_out; pw.W[6]=Wk_out; pw.W[7]=Wv_out;
    pw.WT[0]=WTqo; pw.WT[1]=WTko; pw.WT[2]=WTqi; pw.WT[3]=WTki;
    pw.WT[4]=WTvi; pw.WT[5]=WTqu; pw.WT[6]=WTku; pw.WT[7]=WTvu;
    prep_w_all<<<dim3(4,10,8), 256, 0, stream>>>(pw);

    GemmOut go;
    go.bias[0]=bq_ori; go.bias[1]=bk_ori; go.bias[2]=bq_in; go.bias[3]=bk_in;
    go.bias[4]=bv_in;  go.bias[5]=bq_out; go.bias[6]=bk_out; go.bias[7]=bv_out;
    go.dst[0]=q_ori; go.dst[1]=k_ori; go.dst[2]=qT_in; go.dst[3]=k_in;
    go.dst[4]=vT_in; go.dst[5]=qT_out; go.dst[6]=k_out; go.dst[7]=vT_out;

    // ---- ori branch ----
    proj_gemm<<<dim3(63,8), 256, 0, stream>>>(codeB, WallT, go, 0);      // cols 0..1023
    ms_mfma<<<dim3(16,8,4), 256, 0, stream>>>(q_ori, k_ori, maxscT);
    saoo<<<dim3(16,8), 512, 0, stream>>>(sentB, maxscT, codeT, out);

    // ---- in/out branch (ori scratch now dead; overlay) ----
    zero_pad4<<<dim3(64,4), 256, 0, stream>>>(qT_in, qT_out, vT_in, vT_out);
    proj_gemm<<<dim3(63,12), 256, 0, stream>>>(codeB, WallT, go, 8);     // cols 1024..2559

    AttnArgs aa;
    aa.qT[0]=qT_in;  aa.qT[1]=qT_out;
    aa.kp[0]=k_in;   aa.kp[1]=k_out;
    aa.vT[0]=vT_in;  aa.vT[1]=vT_out;
    attn_fused<<<dim3(64,4,2), 256, 0, stream>>>(aa, sentB, incp, out);
}